// Round 2
// baseline (1946.397 us; speedup 1.0000x reference)
//
#include <hip/hip_runtime.h>
#include <math.h>

#define N_NODES  50000
#define N_EDGES  800000
#define E_TOT    850000   // + self loops
#define N_GRAPHS 512
#define IN_CH    58
#define C1       256      // HEADS1 * H = 4*64
#define H1       4
#define D1       64
#define C2       128
#define NEG_SLOPE 0.2f

// float atomic max via int-pattern trick (works with -inf init)
__device__ __forceinline__ void atomicMaxF(float* addr, float val) {
    if (val >= 0.f) atomicMax((int*)addr, __float_as_int(val));
    else            atomicMin((unsigned int*)addr, __float_as_uint(val));
}

__global__ void k_fill(float* __restrict__ p, int n, float v) {
    int i = blockIdx.x * blockDim.x + threadIdx.x;
    if (i < n) p[i] = v;
}

// h1pre[n, 0:256] = x[n, 0:58] @ W1   (no bias pre-attention, per reference)
__global__ __launch_bounds__(256) void k_gemm1(const float* __restrict__ x,
                                               const float* __restrict__ W1,
                                               float* __restrict__ h1pre) {
    __shared__ float xs[IN_CH];
    int n = blockIdx.x;
    int c = threadIdx.x;
    if (c < IN_CH) xs[c] = x[n * IN_CH + c];
    __syncthreads();
    float acc = 0.f;
#pragma unroll
    for (int k = 0; k < IN_CH; ++k) acc += xs[k] * W1[k * C1 + c];
    h1pre[n * C1 + c] = acc;
}

// per-node, per-head attention logit halves: a_s[n,h], a_d[n,h]
__global__ __launch_bounds__(256) void k_att1(const float* __restrict__ h1pre,
                                              const float* __restrict__ att_s,
                                              const float* __restrict__ att_d,
                                              float* __restrict__ a_s,
                                              float* __restrict__ a_d) {
    int n = blockIdx.x;
    int t = threadIdx.x;              // t = h*64 + d, matches att[h][d] flat
    float v  = h1pre[n * C1 + t];
    float ps = v * att_s[t];
    float pd = v * att_d[t];
#pragma unroll
    for (int o = 32; o > 0; o >>= 1) {
        ps += __shfl_down(ps, o, 64);
        pd += __shfl_down(pd, o, 64);
    }
    if ((t & 63) == 0) {
        int h = t >> 6;
        a_s[n * H1 + h] = ps;
        a_d[n * H1 + h] = pd;
    }
}

// pass 1: e = leaky_relu(a_s[src]+a_d[dst]); segment max into m[dst]
__global__ void k_edge1_max(const int* __restrict__ src, const int* __restrict__ dst,
                            const float* __restrict__ a_s, const float* __restrict__ a_d,
                            float* __restrict__ e1, float* __restrict__ m1) {
    int j = blockIdx.x * blockDim.x + threadIdx.x;
    if (j >= E_TOT) return;
    int s, d;
    if (j < N_EDGES) { s = src[j]; d = dst[j]; } else { s = d = j - N_EDGES; }
#pragma unroll
    for (int h = 0; h < H1; ++h) {
        float e = a_s[s * H1 + h] + a_d[d * H1 + h];
        e = e > 0.f ? e : NEG_SLOPE * e;
        e1[j * H1 + h] = e;
        atomicMaxF(&m1[d * H1 + h], e);
    }
}

// pass 2: ex = exp(e - m[dst]); z[dst] += ex   (e1 overwritten with ex)
__global__ void k_edge1_sum(const int* __restrict__ dst,
                            float* __restrict__ e1, const float* __restrict__ m1,
                            float* __restrict__ z1) {
    int j = blockIdx.x * blockDim.x + threadIdx.x;
    if (j >= E_TOT) return;
    int d = (j < N_EDGES) ? dst[j] : (j - N_EDGES);
#pragma unroll
    for (int h = 0; h < H1; ++h) {
        float ex = expf(e1[j * H1 + h] - m1[d * H1 + h]);
        e1[j * H1 + h] = ex;
        atomicAdd(&z1[d * H1 + h], ex);
    }
}

// pass 3: agg[dst] += h1pre[src] * alpha ; one wave per edge, lane=channel within head
__global__ __launch_bounds__(256) void k_edge1_agg(const int* __restrict__ src, const int* __restrict__ dst,
                                                   const float* __restrict__ ex, const float* __restrict__ z1,
                                                   const float* __restrict__ h1pre,
                                                   float* __restrict__ agg1) {
    int wid  = (blockIdx.x * blockDim.x + threadIdx.x) >> 6;  // edge id
    int lane = threadIdx.x & 63;
    if (wid >= E_TOT) return;
    int j = wid;
    int s, d;
    if (j < N_EDGES) { s = src[j]; d = dst[j]; } else { s = d = j - N_EDGES; }
#pragma unroll
    for (int h = 0; h < H1; ++h) {
        float alpha = ex[j * H1 + h] / (z1[d * H1 + h] + 1e-16f);
        int c = h * D1 + lane;
        atomicAdd(&agg1[d * C1 + c], h1pre[s * C1 + c] * alpha);
    }
}

// h2pre[n, 0:128] = relu(agg1[n,:] + b1) @ W2 ; 2 nodes per 256-thread block
__global__ __launch_bounds__(256) void k_gemm2(const float* __restrict__ agg1,
                                               const float* __restrict__ b1,
                                               const float* __restrict__ W2,
                                               float* __restrict__ h2pre) {
    __shared__ float xs[2][C1];
    int base = blockIdx.x * 2;
    int t = threadIdx.x;
    for (int i = t; i < 2 * C1; i += 256) {
        int nn = i >> 8, k = i & 255;
        float v = agg1[(size_t)(base + nn) * C1 + k] + b1[k];
        xs[nn][k] = v > 0.f ? v : 0.f;
    }
    __syncthreads();
    int which = t >> 7, c = t & 127;
    int n = base + which;
    float acc = 0.f;
#pragma unroll 8
    for (int k = 0; k < C1; ++k) acc += xs[which][k] * W2[k * C2 + c];
    h2pre[(size_t)n * C2 + c] = acc;
}

// a_s2[n] = dot(h2pre[n,:], att_src2) ; one wave per node (4 nodes / block)
__global__ __launch_bounds__(256) void k_att2(const float* __restrict__ h2pre,
                                              const float* __restrict__ att_s,
                                              const float* __restrict__ att_d,
                                              float* __restrict__ a_s,
                                              float* __restrict__ a_d) {
    int n = blockIdx.x * 4 + (threadIdx.x >> 6);
    int lane = threadIdx.x & 63;
    if (n >= N_NODES) return;
    float ps = 0.f, pd = 0.f;
#pragma unroll
    for (int c = lane; c < C2; c += 64) {
        float v = h2pre[(size_t)n * C2 + c];
        ps += v * att_s[c];
        pd += v * att_d[c];
    }
#pragma unroll
    for (int o = 32; o > 0; o >>= 1) {
        ps += __shfl_down(ps, o, 64);
        pd += __shfl_down(pd, o, 64);
    }
    if (lane == 0) { a_s[n] = ps; a_d[n] = pd; }
}

__global__ void k_edge2_max(const int* __restrict__ src, const int* __restrict__ dst,
                            const float* __restrict__ a_s, const float* __restrict__ a_d,
                            float* __restrict__ e2, float* __restrict__ m2) {
    int j = blockIdx.x * blockDim.x + threadIdx.x;
    if (j >= E_TOT) return;
    int s, d;
    if (j < N_EDGES) { s = src[j]; d = dst[j]; } else { s = d = j - N_EDGES; }
    float e = a_s[s] + a_d[d];
    e = e > 0.f ? e : NEG_SLOPE * e;
    e2[j] = e;
    atomicMaxF(&m2[d], e);
}

__global__ void k_edge2_sum(const int* __restrict__ dst,
                            float* __restrict__ e2, const float* __restrict__ m2,
                            float* __restrict__ z2) {
    int j = blockIdx.x * blockDim.x + threadIdx.x;
    if (j >= E_TOT) return;
    int d = (j < N_EDGES) ? dst[j] : (j - N_EDGES);
    float ex = expf(e2[j] - m2[d]);
    e2[j] = ex;
    atomicAdd(&z2[d], ex);
}

__global__ __launch_bounds__(256) void k_edge2_agg(const int* __restrict__ src, const int* __restrict__ dst,
                                                   const float* __restrict__ ex, const float* __restrict__ z2,
                                                   const float* __restrict__ h2pre,
                                                   float* __restrict__ agg2) {
    int wid  = (blockIdx.x * blockDim.x + threadIdx.x) >> 6;
    int lane = threadIdx.x & 63;
    if (wid >= E_TOT) return;
    int j = wid;
    int s, d;
    if (j < N_EDGES) { s = src[j]; d = dst[j]; } else { s = d = j - N_EDGES; }
    float alpha = ex[j] / (z2[d] + 1e-16f);
    atomicAdd(&agg2[(size_t)d * C2 + lane],      h2pre[(size_t)s * C2 + lane]      * alpha);
    atomicAdd(&agg2[(size_t)d * C2 + lane + 64], h2pre[(size_t)s * C2 + lane + 64] * alpha);
}

// pooled[g,c] += relu(agg2[n,c]+b2[c]); cnt[g] += 1
__global__ __launch_bounds__(128) void k_pool(const float* __restrict__ agg2,
                                              const float* __restrict__ b2,
                                              const int* __restrict__ batch,
                                              float* __restrict__ pooled,
                                              float* __restrict__ cnt) {
    int n = blockIdx.x;
    int c = threadIdx.x;
    int g = batch[n];
    float v = agg2[(size_t)n * C2 + c] + b2[c];
    v = v > 0.f ? v : 0.f;
    atomicAdd(&pooled[g * C2 + c], v);
    if (c == 0) atomicAdd(&cnt[g], 1.0f);
}

// BatchNorm over 512 graphs per channel; block = channel, 512 threads = graphs
__global__ __launch_bounds__(512) void k_bn(const float* __restrict__ pooled,
                                            const float* __restrict__ cnt,
                                            const float* __restrict__ gamma,
                                            const float* __restrict__ beta,
                                            float* __restrict__ out) {
    int c = blockIdx.x;
    int g = threadIdx.x;
    __shared__ float red[512];
    __shared__ float s_mu, s_var;
    float v = pooled[g * C2 + c] / fmaxf(cnt[g], 1.0f);
    red[g] = v;
    __syncthreads();
    for (int s = 256; s > 0; s >>= 1) {
        if (g < s) red[g] += red[g + s];
        __syncthreads();
    }
    if (g == 0) s_mu = red[0] * (1.0f / N_GRAPHS);
    __syncthreads();
    float dv = v - s_mu;
    red[g] = dv * dv;
    __syncthreads();
    for (int s = 256; s > 0; s >>= 1) {
        if (g < s) red[g] += red[g + s];
        __syncthreads();
    }
    if (g == 0) s_var = red[0] * (1.0f / N_GRAPHS);
    __syncthreads();
    out[g * C2 + c] = dv * rsqrtf(s_var + 1e-5f) * gamma[c] + beta[c];
}

extern "C" void kernel_launch(void* const* d_in, const int* in_sizes, int n_in,
                              void* d_out, int out_size, void* d_ws, size_t ws_size,
                              hipStream_t stream) {
    const float* x     = (const float*)d_in[0];
    const int*   eidx  = (const int*)d_in[1];
    const int*   batch = (const int*)d_in[2];
    const float* W1    = (const float*)d_in[3];
    const float* atts1 = (const float*)d_in[4];
    const float* attd1 = (const float*)d_in[5];
    const float* b1    = (const float*)d_in[6];
    const float* W2    = (const float*)d_in[7];
    const float* atts2 = (const float*)d_in[8];
    const float* attd2 = (const float*)d_in[9];
    const float* b2    = (const float*)d_in[10];
    const float* gamma = (const float*)d_in[11];
    const float* beta  = (const float*)d_in[12];
    float* out = (float*)d_out;
    float* ws  = (float*)d_ws;

    const int* src = eidx;
    const int* dst = eidx + N_EDGES;

    // workspace layout (fp32 elements)
    // e2 (850,000) overlays dead h1pre region in layer2; h2pre overlays dead e1.
    // [o_m1, o_m2] contiguous 250,000 elems -> one -inf fill.
    // [o_agg1 .. end] contiguous -> one zero memset.
    const size_t o_h1pre = 0;               // 12,800,000 (layer1)
    const size_t o_e1    = 12800000;        // 3,400,000 (layer1)
    const size_t o_h2pre = 12800000;        // 6,400,000 (layer2, reuses e1 region)
    const size_t o_e2    = 0;               // 850,000 (layer2, reuses h1pre region)
    const size_t o_as1   = 19200000;        // 200,000
    const size_t o_ad1   = 19400000;        // 200,000
    const size_t o_as2   = 19600000;        // 50,000
    const size_t o_ad2   = 19650000;        // 50,000
    const size_t o_m1    = 19700000;        // 200,000  (-inf fill)
    const size_t o_m2    = 19900000;        // 50,000   (-inf fill)
    const size_t o_agg1  = 19950000;        // 12,800,000 (zero)
    const size_t o_agg2  = 32750000;        // 6,400,000  (zero)
    const size_t o_z1    = 39150000;        // 200,000    (zero)
    const size_t o_z2    = 39350000;        // 50,000     (zero)
    const size_t o_pool  = 39400000;        // 65,536     (zero)
    const size_t o_cnt   = 39465536;        // 512        (zero)
    const size_t total   = 39466048;        // ~158 MB

    // init
    k_fill<<<(250000 + 255) / 256, 256, 0, stream>>>(ws + o_m1, 250000, -INFINITY);
    hipMemsetAsync(ws + o_agg1, 0, (total - o_agg1) * sizeof(float), stream);

    // ---- layer 1 ----
    k_gemm1<<<N_NODES, 256, 0, stream>>>(x, W1, ws + o_h1pre);
    k_att1<<<N_NODES, 256, 0, stream>>>(ws + o_h1pre, atts1, attd1, ws + o_as1, ws + o_ad1);
    k_edge1_max<<<(E_TOT + 255) / 256, 256, 0, stream>>>(src, dst, ws + o_as1, ws + o_ad1,
                                                         ws + o_e1, ws + o_m1);
    k_edge1_sum<<<(E_TOT + 255) / 256, 256, 0, stream>>>(dst, ws + o_e1, ws + o_m1, ws + o_z1);
    k_edge1_agg<<<(E_TOT * 64 + 255) / 256, 256, 0, stream>>>(src, dst, ws + o_e1, ws + o_z1,
                                                              ws + o_h1pre, ws + o_agg1);

    // ---- layer 2 ----
    k_gemm2<<<N_NODES / 2, 256, 0, stream>>>(ws + o_agg1, b1, W2, ws + o_h2pre);
    k_att2<<<(N_NODES + 3) / 4, 256, 0, stream>>>(ws + o_h2pre, atts2, attd2, ws + o_as2, ws + o_ad2);
    k_edge2_max<<<(E_TOT + 255) / 256, 256, 0, stream>>>(src, dst, ws + o_as2, ws + o_ad2,
                                                         ws + o_e2, ws + o_m2);
    k_edge2_sum<<<(E_TOT + 255) / 256, 256, 0, stream>>>(dst, ws + o_e2, ws + o_m2, ws + o_z2);
    k_edge2_agg<<<(E_TOT * 64 + 255) / 256, 256, 0, stream>>>(src, dst, ws + o_e2, ws + o_z2,
                                                              ws + o_h2pre, ws + o_agg2);

    // ---- pool + BN ----
    k_pool<<<N_NODES, 128, 0, stream>>>(ws + o_agg2, b2, batch, ws + o_pool, ws + o_cnt);
    k_bn<<<C2, 512, 0, stream>>>(ws + o_pool, ws + o_cnt, gamma, beta, out);
}

// Round 3
// 709.641 us; speedup vs baseline: 2.7428x; 2.7428x over previous
//
#include <hip/hip_runtime.h>
#include <math.h>

#define N_NODES  50000
#define N_EDGES  800000
#define E_TOT    850000   // + self loops
#define N_GRAPHS 512
#define IN_CH    58
#define C1       256      // HEADS1 * H = 4*64
#define H1       4
#define C2       128
#define NEG_SLOPE 0.2f
#define NBLK     196      // ceil(50000/256) scan blocks

// ---------------- CSR build ----------------

__global__ void k_hist(const int* __restrict__ src, const int* __restrict__ dst,
                       int* __restrict__ deg) {
    int j = blockIdx.x * blockDim.x + threadIdx.x;
    if (j >= E_TOT) return;
    int d = (j < N_EDGES) ? dst[j] : (j - N_EDGES);
    atomicAdd(&deg[d], 1);
}

__global__ __launch_bounds__(256) void k_scan1(const int* __restrict__ deg,
                                               int* __restrict__ incl,
                                               int* __restrict__ bsum) {
    __shared__ int sh[256];
    int t = threadIdx.x;
    int j = blockIdx.x * 256 + t;
    int v = (j < N_NODES) ? deg[j] : 0;
    sh[t] = v;
    __syncthreads();
    for (int o = 1; o < 256; o <<= 1) {
        int u = (t >= o) ? sh[t - o] : 0;
        __syncthreads();
        sh[t] += u;
        __syncthreads();
    }
    incl[j] = sh[t];                         // incl padded to 50176
    if (t == 255) bsum[blockIdx.x] = sh[255];
}

__global__ __launch_bounds__(256) void k_scan2(const int* __restrict__ bsum,
                                               int* __restrict__ boff) {
    __shared__ int sh[256];
    int t = threadIdx.x;
    int v = (t < NBLK) ? bsum[t] : 0;
    sh[t] = v;
    __syncthreads();
    for (int o = 1; o < 256; o <<= 1) {
        int u = (t >= o) ? sh[t - o] : 0;
        __syncthreads();
        sh[t] += u;
        __syncthreads();
    }
    boff[t] = sh[t] - v;                     // exclusive
}

// row_ptr[j+1] = boff[b] + incl[j]; also graph node counts
__global__ __launch_bounds__(256) void k_scan3(const int* __restrict__ incl,
                                               const int* __restrict__ boff,
                                               const int* __restrict__ batch,
                                               int* __restrict__ row_ptr,
                                               float* __restrict__ cnt) {
    int j = blockIdx.x * 256 + threadIdx.x;
    if (j >= N_NODES) return;
    row_ptr[j + 1] = boff[blockIdx.x] + incl[j];
    if (j == 0) row_ptr[0] = 0;
    atomicAdd(&cnt[batch[j]], 1.0f);
}

__global__ void k_scatter(const int* __restrict__ src, const int* __restrict__ dst,
                          const int* __restrict__ row_ptr, int* __restrict__ cursor,
                          int* __restrict__ csrc) {
    int j = blockIdx.x * blockDim.x + threadIdx.x;
    if (j >= E_TOT) return;
    int s, d;
    if (j < N_EDGES) { s = src[j]; d = dst[j]; } else { s = d = j - N_EDGES; }
    int pos = atomicAdd(&cursor[d], 1);
    csrc[row_ptr[d] + pos] = s;
}

// ---------------- layer 1 ----------------

// h1pre = x @ W1 ; fused per-head attention logit halves a_s1/a_d1
__global__ __launch_bounds__(256) void k_gemm1_att(const float* __restrict__ x,
                                                   const float* __restrict__ W1,
                                                   const float* __restrict__ atts,
                                                   const float* __restrict__ attd,
                                                   float* __restrict__ h1pre,
                                                   float* __restrict__ a_s,
                                                   float* __restrict__ a_d) {
    __shared__ float xs[IN_CH];
    int n = blockIdx.x;
    int t = threadIdx.x;
    if (t < IN_CH) xs[t] = x[n * IN_CH + t];
    __syncthreads();
    float acc = 0.f;
#pragma unroll
    for (int k = 0; k < IN_CH; ++k) acc += xs[k] * W1[k * C1 + t];
    h1pre[(size_t)n * C1 + t] = acc;
    float ps = acc * atts[t];
    float pd = acc * attd[t];
#pragma unroll
    for (int o = 32; o > 0; o >>= 1) {
        ps += __shfl_down(ps, o, 64);
        pd += __shfl_down(pd, o, 64);
    }
    if ((t & 63) == 0) {
        int h = t >> 6;
        a_s[n * H1 + h] = ps;
        a_d[n * H1 + h] = pd;
    }
}

// fused softmax + aggregate + bias + relu, per dst node, CSR gather. 4 heads.
// block = node, 256 threads: wave h owns head h; channel c = t.
__global__ __launch_bounds__(256) void k_l1_agg(const int* __restrict__ row_ptr,
                                                const int* __restrict__ csrc,
                                                const float* __restrict__ a_s,
                                                const float* __restrict__ a_d,
                                                const float* __restrict__ h1pre,
                                                const float* __restrict__ b1,
                                                float* __restrict__ h1out) {
    int d = blockIdx.x;
    int t = threadIdx.x;
    int lane = t & 63, h = t >> 6;
    int beg = row_ptr[d];
    int deg = row_ptr[d + 1] - beg;
    float ad = a_d[d * H1 + h];

    // online softmax (m,z) over this head's edges, strided across the wave
    float m = -1e30f, z = 0.f;
    for (int i = lane; i < deg; i += 64) {
        int s = csrc[beg + i];
        float e = a_s[s * H1 + h] + ad;
        e = e > 0.f ? e : NEG_SLOPE * e;
        float M = fmaxf(m, e);
        z = z * __expf(m - M) + __expf(e - M);
        m = M;
    }
#pragma unroll
    for (int o = 32; o > 0; o >>= 1) {
        float m2 = __shfl_down(m, o, 64);
        float z2 = __shfl_down(z, o, 64);
        float M = fmaxf(m, m2);
        z = z * __expf(m - M) + z2 * __expf(m2 - M);
        m = M;
    }
    __shared__ float sm[H1], sinv[H1];
    if (lane == 0) { sm[h] = m; sinv[h] = 1.f / z; }  // z >= 1 (max edge term)
    __syncthreads();
    float mh = sm[h], invh = sinv[h];

    __shared__ int   ssrc[64];
    __shared__ float sex[64][H1];
    float acc = 0.f;
    int c = t;   // channel = h*64 + lane, matches head blocks of h1pre
    for (int chunk = 0; chunk < deg; chunk += 64) {
        int rem = min(64, deg - chunk);
        __syncthreads();
        int i = t & 63;
        if (i < rem) {
            int s = csrc[beg + chunk + i];
            if (h == 0) ssrc[i] = s;
            float e = a_s[s * H1 + h] + ad;
            e = e > 0.f ? e : NEG_SLOPE * e;
            sex[i][h] = __expf(e - mh) * invh;
        }
        __syncthreads();
        for (int i2 = 0; i2 < rem; ++i2)
            acc += sex[i2][h] * h1pre[(size_t)ssrc[i2] * C1 + c];
    }
    float v = acc + b1[c];
    h1out[(size_t)d * C1 + c] = v > 0.f ? v : 0.f;
}

// ---------------- layer 2 ----------------

// h2pre = h1 @ W2 ; fused attention logits (1 head). 2 nodes / 256-thread block.
__global__ __launch_bounds__(256) void k_gemm2_att(const float* __restrict__ h1,
                                                   const float* __restrict__ W2,
                                                   const float* __restrict__ atts,
                                                   const float* __restrict__ attd,
                                                   float* __restrict__ h2pre,
                                                   float* __restrict__ a_s,
                                                   float* __restrict__ a_d) {
    __shared__ float xs[2][C1];
    __shared__ float rs[4], rd[4];
    int base = blockIdx.x * 2;
    int t = threadIdx.x;
    for (int i = t; i < 2 * C1; i += 256) {
        int nn = i >> 8, k = i & 255;
        xs[nn][k] = h1[(size_t)(base + nn) * C1 + k];
    }
    __syncthreads();
    int which = t >> 7, c = t & 127;
    float acc = 0.f;
#pragma unroll 8
    for (int k = 0; k < C1; ++k) acc += xs[which][k] * W2[k * C2 + c];
    h2pre[(size_t)(base + which) * C2 + c] = acc;
    float ps = acc * atts[c];
    float pd = acc * attd[c];
#pragma unroll
    for (int o = 32; o > 0; o >>= 1) {
        ps += __shfl_down(ps, o, 64);
        pd += __shfl_down(pd, o, 64);
    }
    int w = t >> 6;
    if ((t & 63) == 0) { rs[w] = ps; rd[w] = pd; }
    __syncthreads();
    if (t < 2) {
        a_s[base + t] = rs[2 * t] + rs[2 * t + 1];
        a_d[base + t] = rd[2 * t] + rd[2 * t + 1];
    }
}

// fused softmax + aggregate + bias + relu + mean-pool accumulation.
// block = node, 128 threads (2 waves), channel c = t.
__global__ __launch_bounds__(128) void k_l2_aggpool(const int* __restrict__ row_ptr,
                                                    const int* __restrict__ csrc,
                                                    const float* __restrict__ a_s,
                                                    const float* __restrict__ a_d,
                                                    const float* __restrict__ h2pre,
                                                    const float* __restrict__ b2,
                                                    const int* __restrict__ batch,
                                                    float* __restrict__ pooled) {
    int d = blockIdx.x;
    int t = threadIdx.x;
    int lane = t & 63, w = t >> 6;
    int beg = row_ptr[d];
    int deg = row_ptr[d + 1] - beg;
    float ad = a_d[d];

    float m = -1e30f, z = 0.f;
    for (int i = t; i < deg; i += 128) {
        int s = csrc[beg + i];
        float e = a_s[s] + ad;
        e = e > 0.f ? e : NEG_SLOPE * e;
        float M = fmaxf(m, e);
        z = z * __expf(m - M) + __expf(e - M);
        m = M;
    }
#pragma unroll
    for (int o = 32; o > 0; o >>= 1) {
        float m2 = __shfl_down(m, o, 64);
        float z2 = __shfl_down(z, o, 64);
        float M = fmaxf(m, m2);
        z = z * __expf(m - M) + z2 * __expf(m2 - M);
        m = M;
    }
    __shared__ float rm[2], rz[2];
    __shared__ float smv, sinv;
    if (lane == 0) { rm[w] = m; rz[w] = z; }
    __syncthreads();
    if (t == 0) {
        float M = fmaxf(rm[0], rm[1]);
        float Z = rz[0] * __expf(rm[0] - M) + rz[1] * __expf(rm[1] - M);
        smv = M; sinv = 1.f / Z;
    }
    __syncthreads();
    float mh = smv, invh = sinv;

    __shared__ int   ssrc[128];
    __shared__ float sex[128];
    float acc = 0.f;
    for (int chunk = 0; chunk < deg; chunk += 128) {
        int rem = min(128, deg - chunk);
        __syncthreads();
        if (t < rem) {
            int s = csrc[beg + chunk + t];
            ssrc[t] = s;
            float e = a_s[s] + ad;
            e = e > 0.f ? e : NEG_SLOPE * e;
            sex[t] = __expf(e - mh) * invh;
        }
        __syncthreads();
        for (int i = 0; i < rem; ++i)
            acc += sex[i] * h2pre[(size_t)ssrc[i] * C2 + t];
    }
    float v = acc + b2[t];
    v = v > 0.f ? v : 0.f;
    int g = batch[d];
    atomicAdd(&pooled[g * C2 + t], v);
}

// ---------------- BN ----------------

__global__ __launch_bounds__(512) void k_bn(const float* __restrict__ pooled,
                                            const float* __restrict__ cnt,
                                            const float* __restrict__ gamma,
                                            const float* __restrict__ beta,
                                            float* __restrict__ out) {
    int c = blockIdx.x;
    int g = threadIdx.x;
    __shared__ float red[512];
    __shared__ float s_mu, s_var;
    float v = pooled[g * C2 + c] / fmaxf(cnt[g], 1.0f);
    red[g] = v;
    __syncthreads();
    for (int s = 256; s > 0; s >>= 1) {
        if (g < s) red[g] += red[g + s];
        __syncthreads();
    }
    if (g == 0) s_mu = red[0] * (1.0f / N_GRAPHS);
    __syncthreads();
    float dv = v - s_mu;
    red[g] = dv * dv;
    __syncthreads();
    for (int s = 256; s > 0; s >>= 1) {
        if (g < s) red[g] += red[g + s];
        __syncthreads();
    }
    if (g == 0) s_var = red[0] * (1.0f / N_GRAPHS);
    __syncthreads();
    out[g * C2 + c] = dv * rsqrtf(s_var + 1e-5f) * gamma[c] + beta[c];
}

extern "C" void kernel_launch(void* const* d_in, const int* in_sizes, int n_in,
                              void* d_out, int out_size, void* d_ws, size_t ws_size,
                              hipStream_t stream) {
    const float* x     = (const float*)d_in[0];
    const int*   eidx  = (const int*)d_in[1];
    const int*   batch = (const int*)d_in[2];
    const float* W1    = (const float*)d_in[3];
    const float* atts1 = (const float*)d_in[4];
    const float* attd1 = (const float*)d_in[5];
    const float* b1    = (const float*)d_in[6];
    const float* W2    = (const float*)d_in[7];
    const float* atts2 = (const float*)d_in[8];
    const float* attd2 = (const float*)d_in[9];
    const float* b2    = (const float*)d_in[10];
    const float* gamma = (const float*)d_in[11];
    const float* beta  = (const float*)d_in[12];
    float* out = (float*)d_out;
    float* ws  = (float*)d_ws;

    const int* src = eidx;
    const int* dst = eidx + N_EDGES;

    // workspace layout, element offsets (fp32/int32)
    const size_t o_h1pre  = 0;           // 12,800,000
    const size_t o_h1     = 12800000;    // 12,800,000
    const size_t o_h2pre  = 25600000;    // 6,400,000
    const size_t o_as1    = 32000000;    // 200,000
    const size_t o_ad1    = 32200000;    // 200,000
    const size_t o_as2    = 32400000;    // 50,000
    const size_t o_ad2    = 32450000;    // 50,000
    const size_t o_incl   = 32500000;    // 50,176 (padded)
    const size_t o_bsum   = 32550176;    // 256
    const size_t o_boff   = 32550432;    // 256
    const size_t o_rowptr = 32550688;    // 50,004
    const size_t o_csrc   = 32600692;    // 850,000
    // ---- contiguous zero block from here ----
    const size_t o_deg    = 33450692;    // 50,176
    const size_t o_cursor = 33500868;    // 50,000
    const size_t o_pool   = 33550868;    // 65,536
    const size_t o_cnt    = 33616404;    // 512
    const size_t total    = 33616916;    // ~134.5 MB

    int* p_incl   = (int*)(ws + o_incl);
    int* p_bsum   = (int*)(ws + o_bsum);
    int* p_boff   = (int*)(ws + o_boff);
    int* p_rowptr = (int*)(ws + o_rowptr);
    int* p_csrc   = (int*)(ws + o_csrc);
    int* p_deg    = (int*)(ws + o_deg);
    int* p_cursor = (int*)(ws + o_cursor);

    hipMemsetAsync(ws + o_deg, 0, (total - o_deg) * sizeof(float), stream);

    // ---- CSR build ----
    k_hist<<<(E_TOT + 255) / 256, 256, 0, stream>>>(src, dst, p_deg);
    k_scan1<<<NBLK, 256, 0, stream>>>(p_deg, p_incl, p_bsum);
    k_scan2<<<1, 256, 0, stream>>>(p_bsum, p_boff);
    k_scan3<<<NBLK, 256, 0, stream>>>(p_incl, p_boff, batch, p_rowptr, ws + o_cnt);
    k_scatter<<<(E_TOT + 255) / 256, 256, 0, stream>>>(src, dst, p_rowptr, p_cursor, p_csrc);

    // ---- layer 1 ----
    k_gemm1_att<<<N_NODES, 256, 0, stream>>>(x, W1, atts1, attd1,
                                             ws + o_h1pre, ws + o_as1, ws + o_ad1);
    k_l1_agg<<<N_NODES, 256, 0, stream>>>(p_rowptr, p_csrc, ws + o_as1, ws + o_ad1,
                                          ws + o_h1pre, b1, ws + o_h1);

    // ---- layer 2 ----
    k_gemm2_att<<<N_NODES / 2, 256, 0, stream>>>(ws + o_h1, W2, atts2, attd2,
                                                 ws + o_h2pre, ws + o_as2, ws + o_ad2);
    k_l2_aggpool<<<N_NODES, 128, 0, stream>>>(p_rowptr, p_csrc, ws + o_as2, ws + o_ad2,
                                              ws + o_h2pre, b2, batch, ws + o_pool);

    // ---- BN ----
    k_bn<<<C2, 512, 0, stream>>>(ws + o_pool, ws + o_cnt, gamma, beta, out);
}

// Round 4
// 556.117 us; speedup vs baseline: 3.5000x; 1.2761x over previous
//
#include <hip/hip_runtime.h>
#include <math.h>

#define N_NODES  50000
#define N_EDGES  800000
#define E_TOT    850000   // + self loops
#define N_GRAPHS 512
#define IN_CH    58
#define C1       256      // HEADS1 * H = 4*64
#define H1       4
#define C2       128
#define NEG_SLOPE 0.2f
#define NBLK     196      // ceil(50000/256) scan blocks

// ---------------- CSR build ----------------

__global__ void k_hist(const int* __restrict__ src, const int* __restrict__ dst,
                       int* __restrict__ deg) {
    int j = blockIdx.x * blockDim.x + threadIdx.x;
    if (j >= E_TOT) return;
    int d = (j < N_EDGES) ? dst[j] : (j - N_EDGES);
    atomicAdd(&deg[d], 1);
}

__global__ __launch_bounds__(256) void k_scan1(const int* __restrict__ deg,
                                               int* __restrict__ incl,
                                               int* __restrict__ bsum) {
    __shared__ int sh[256];
    int t = threadIdx.x;
    int j = blockIdx.x * 256 + t;
    int v = (j < N_NODES) ? deg[j] : 0;
    sh[t] = v;
    __syncthreads();
    for (int o = 1; o < 256; o <<= 1) {
        int u = (t >= o) ? sh[t - o] : 0;
        __syncthreads();
        sh[t] += u;
        __syncthreads();
    }
    incl[j] = sh[t];                         // incl padded to 50176
    if (t == 255) bsum[blockIdx.x] = sh[255];
}

__global__ __launch_bounds__(256) void k_scan2(const int* __restrict__ bsum,
                                               int* __restrict__ boff) {
    __shared__ int sh[256];
    int t = threadIdx.x;
    int v = (t < NBLK) ? bsum[t] : 0;
    sh[t] = v;
    __syncthreads();
    for (int o = 1; o < 256; o <<= 1) {
        int u = (t >= o) ? sh[t - o] : 0;
        __syncthreads();
        sh[t] += u;
        __syncthreads();
    }
    boff[t] = sh[t] - v;                     // exclusive
}

// row_ptr[j+1] = boff[b] + incl[j]; also graph node counts
__global__ __launch_bounds__(256) void k_scan3(const int* __restrict__ incl,
                                               const int* __restrict__ boff,
                                               const int* __restrict__ batch,
                                               int* __restrict__ row_ptr,
                                               float* __restrict__ cnt) {
    int j = blockIdx.x * 256 + threadIdx.x;
    if (j >= N_NODES) return;
    row_ptr[j + 1] = boff[blockIdx.x] + incl[j];
    if (j == 0) row_ptr[0] = 0;
    atomicAdd(&cnt[batch[j]], 1.0f);
}

__global__ void k_scatter(const int* __restrict__ src, const int* __restrict__ dst,
                          const int* __restrict__ row_ptr, int* __restrict__ cursor,
                          int* __restrict__ csrc) {
    int j = blockIdx.x * blockDim.x + threadIdx.x;
    if (j >= E_TOT) return;
    int s, d;
    if (j < N_EDGES) { s = src[j]; d = dst[j]; } else { s = d = j - N_EDGES; }
    int pos = atomicAdd(&cursor[d], 1);
    csrc[row_ptr[d] + pos] = s;
}

// ---------------- layer 1 GEMM (tiled) ----------------
// C tile 64 nodes x 256 ch; whole W1 (58x256) + x-tile in LDS; 8x8 per thread.
__global__ __launch_bounds__(256) void k_gemm1(const float* __restrict__ x,
                                               const float* __restrict__ W1,
                                               float* __restrict__ h1pre) {
    __shared__ float Xs[64][60];      // node-major, 58 padded to 60
    __shared__ float Ws[IN_CH][C1];   // 59392 B
    int m0 = blockIdx.x * 64;
    int t = threadIdx.x;
    // x tile: coalesced scalar copy
    for (int idx = t; idx < 64 * IN_CH; idx += 256) {
        int m = idx / IN_CH, k = idx - m * IN_CH;
        int n = m0 + m;
        Xs[m][k] = (n < N_NODES) ? x[(size_t)n * IN_CH + k] : 0.f;
    }
    // W1: float4 copy
    for (int idx = t * 4; idx < IN_CH * C1; idx += 1024) {
        *(float4*)(&Ws[0][0] + idx) = *(const float4*)(W1 + idx);
    }
    __syncthreads();
    int tr = t >> 5, tc = t & 31;     // nodes tr*8+i, channels tc+32*j
    float acc[8][8] = {{0.f}};
    for (int kk = 0; kk < IN_CH; ++kk) {
        float a[8], b[8];
#pragma unroll
        for (int i = 0; i < 8; ++i) a[i] = Xs[tr * 8 + i][kk];
#pragma unroll
        for (int j = 0; j < 8; ++j) b[j] = Ws[kk][tc + 32 * j];
#pragma unroll
        for (int i = 0; i < 8; ++i)
#pragma unroll
            for (int j = 0; j < 8; ++j) acc[i][j] += a[i] * b[j];
    }
#pragma unroll
    for (int i = 0; i < 8; ++i) {
        int n = m0 + tr * 8 + i;
        if (n < N_NODES) {
#pragma unroll
            for (int j = 0; j < 8; ++j)
                h1pre[(size_t)n * C1 + tc + 32 * j] = acc[i][j];
        }
    }
}

// per-node per-head attention logits from h1pre
__global__ __launch_bounds__(256) void k_att1(const float* __restrict__ h1pre,
                                              const float* __restrict__ att_s,
                                              const float* __restrict__ att_d,
                                              float* __restrict__ a_s,
                                              float* __restrict__ a_d) {
    int n = blockIdx.x;
    int t = threadIdx.x;
    float v  = h1pre[(size_t)n * C1 + t];
    float ps = v * att_s[t];
    float pd = v * att_d[t];
#pragma unroll
    for (int o = 32; o > 0; o >>= 1) {
        ps += __shfl_down(ps, o, 64);
        pd += __shfl_down(pd, o, 64);
    }
    if ((t & 63) == 0) {
        int h = t >> 6;
        a_s[n * H1 + h] = ps;
        a_d[n * H1 + h] = pd;
    }
}

// fused softmax + aggregate + bias + relu, per dst node, CSR gather. 4 heads.
__global__ __launch_bounds__(256) void k_l1_agg(const int* __restrict__ row_ptr,
                                                const int* __restrict__ csrc,
                                                const float* __restrict__ a_s,
                                                const float* __restrict__ a_d,
                                                const float* __restrict__ h1pre,
                                                const float* __restrict__ b1,
                                                float* __restrict__ h1out) {
    int d = blockIdx.x;
    int t = threadIdx.x;
    int lane = t & 63, h = t >> 6;
    int beg = row_ptr[d];
    int deg = row_ptr[d + 1] - beg;
    float ad = a_d[d * H1 + h];

    float m = -1e30f, z = 0.f;
    for (int i = lane; i < deg; i += 64) {
        int s = csrc[beg + i];
        float e = a_s[s * H1 + h] + ad;
        e = e > 0.f ? e : NEG_SLOPE * e;
        float M = fmaxf(m, e);
        z = z * __expf(m - M) + __expf(e - M);
        m = M;
    }
#pragma unroll
    for (int o = 32; o > 0; o >>= 1) {
        float m2 = __shfl_down(m, o, 64);
        float z2 = __shfl_down(z, o, 64);
        float M = fmaxf(m, m2);
        z = z * __expf(m - M) + z2 * __expf(m2 - M);
        m = M;
    }
    __shared__ float sm[H1], sinv[H1];
    if (lane == 0) { sm[h] = m; sinv[h] = 1.f / z; }
    __syncthreads();
    float mh = sm[h], invh = sinv[h];

    __shared__ int   ssrc[64];
    __shared__ float sex[64][H1];
    float acc = 0.f;
    int c = t;
    for (int chunk = 0; chunk < deg; chunk += 64) {
        int rem = min(64, deg - chunk);
        __syncthreads();
        int i = t & 63;
        if (i < rem) {
            int s = csrc[beg + chunk + i];
            if (h == 0) ssrc[i] = s;
            float e = a_s[s * H1 + h] + ad;
            e = e > 0.f ? e : NEG_SLOPE * e;
            sex[i][h] = __expf(e - mh) * invh;
        }
        __syncthreads();
        for (int i2 = 0; i2 < rem; ++i2)
            acc += sex[i2][h] * h1pre[(size_t)ssrc[i2] * C1 + c];
    }
    float v = acc + b1[c];
    h1out[(size_t)d * C1 + c] = v > 0.f ? v : 0.f;
}

// ---------------- layer 2 GEMM (tiled) ----------------
// C tile 128 nodes x 128 ch; BK=64; 8x8 per thread.
__global__ __launch_bounds__(256) void k_gemm2(const float* __restrict__ h1,
                                               const float* __restrict__ W2,
                                               float* __restrict__ h2pre) {
    __shared__ float As[128][68];     // node-major, 64 padded to 68
    __shared__ float Bs[64][C2];
    int m0 = blockIdx.x * 128;
    int t = threadIdx.x;
    int tr = t >> 4, tc = t & 15;     // nodes tr*8+i, channels tc+16*j
    float acc[8][8] = {{0.f}};
    for (int k0 = 0; k0 < C1; k0 += 64) {
        __syncthreads();
        // A tile: 128 rows x 64, float4 coalesced
        {
            int mm  = t >> 4;          // 0..15
            int kk4 = (t & 15) * 4;    // 0..60
#pragma unroll
            for (int it = 0; it < 8; ++it) {
                int m = mm + 16 * it;
                int n = m0 + m;
                float4 v;
                if (n < N_NODES) v = *(const float4*)(h1 + (size_t)n * C1 + k0 + kk4);
                else             v = make_float4(0.f, 0.f, 0.f, 0.f);
                *(float4*)(&As[m][kk4]) = v;
            }
        }
        // B tile: 64 x 128 float4 copy
        {
            int kB = t >> 5;           // 0..7
            int cB = (t & 31) * 4;     // 0..124
#pragma unroll
            for (int it = 0; it < 8; ++it) {
                int k = kB + 8 * it;
                *(float4*)(&Bs[k][cB]) = *(const float4*)(W2 + (size_t)(k0 + k) * C2 + cB);
            }
        }
        __syncthreads();
        for (int kk = 0; kk < 64; ++kk) {
            float a[8], b[8];
#pragma unroll
            for (int i = 0; i < 8; ++i) a[i] = As[tr * 8 + i][kk];
#pragma unroll
            for (int j = 0; j < 8; ++j) b[j] = Bs[kk][tc + 16 * j];
#pragma unroll
            for (int i = 0; i < 8; ++i)
#pragma unroll
                for (int j = 0; j < 8; ++j) acc[i][j] += a[i] * b[j];
        }
    }
#pragma unroll
    for (int i = 0; i < 8; ++i) {
        int n = m0 + tr * 8 + i;
        if (n < N_NODES) {
#pragma unroll
            for (int j = 0; j < 8; ++j)
                h2pre[(size_t)n * C2 + tc + 16 * j] = acc[i][j];
        }
    }
}

// attention logits layer 2 (1 head); 4 nodes per 256-thread block
__global__ __launch_bounds__(256) void k_att2(const float* __restrict__ h2pre,
                                              const float* __restrict__ att_s,
                                              const float* __restrict__ att_d,
                                              float* __restrict__ a_s,
                                              float* __restrict__ a_d) {
    int n = blockIdx.x * 4 + (threadIdx.x >> 6);
    int lane = threadIdx.x & 63;
    if (n >= N_NODES) return;
    float ps = 0.f, pd = 0.f;
#pragma unroll
    for (int c = lane; c < C2; c += 64) {
        float v = h2pre[(size_t)n * C2 + c];
        ps += v * att_s[c];
        pd += v * att_d[c];
    }
#pragma unroll
    for (int o = 32; o > 0; o >>= 1) {
        ps += __shfl_down(ps, o, 64);
        pd += __shfl_down(pd, o, 64);
    }
    if (lane == 0) { a_s[n] = ps; a_d[n] = pd; }
}

// fused softmax + aggregate + bias + relu + mean-pool accumulation.
__global__ __launch_bounds__(128) void k_l2_aggpool(const int* __restrict__ row_ptr,
                                                    const int* __restrict__ csrc,
                                                    const float* __restrict__ a_s,
                                                    const float* __restrict__ a_d,
                                                    const float* __restrict__ h2pre,
                                                    const float* __restrict__ b2,
                                                    const int* __restrict__ batch,
                                                    float* __restrict__ pooled) {
    int d = blockIdx.x;
    int t = threadIdx.x;
    int lane = t & 63, w = t >> 6;
    int beg = row_ptr[d];
    int deg = row_ptr[d + 1] - beg;
    float ad = a_d[d];

    float m = -1e30f, z = 0.f;
    for (int i = t; i < deg; i += 128) {
        int s = csrc[beg + i];
        float e = a_s[s] + ad;
        e = e > 0.f ? e : NEG_SLOPE * e;
        float M = fmaxf(m, e);
        z = z * __expf(m - M) + __expf(e - M);
        m = M;
    }
#pragma unroll
    for (int o = 32; o > 0; o >>= 1) {
        float m2 = __shfl_down(m, o, 64);
        float z2 = __shfl_down(z, o, 64);
        float M = fmaxf(m, m2);
        z = z * __expf(m - M) + z2 * __expf(m2 - M);
        m = M;
    }
    __shared__ float rm[2], rz[2];
    __shared__ float smv, sinv;
    if (lane == 0) { rm[w] = m; rz[w] = z; }
    __syncthreads();
    if (t == 0) {
        float M = fmaxf(rm[0], rm[1]);
        float Z = rz[0] * __expf(rm[0] - M) + rz[1] * __expf(rm[1] - M);
        smv = M; sinv = 1.f / Z;
    }
    __syncthreads();
    float mh = smv, invh = sinv;

    __shared__ int   ssrc[128];
    __shared__ float sex[128];
    float acc = 0.f;
    for (int chunk = 0; chunk < deg; chunk += 128) {
        int rem = min(128, deg - chunk);
        __syncthreads();
        if (t < rem) {
            int s = csrc[beg + chunk + t];
            ssrc[t] = s;
            float e = a_s[s] + ad;
            e = e > 0.f ? e : NEG_SLOPE * e;
            sex[t] = __expf(e - mh) * invh;
        }
        __syncthreads();
        for (int i = 0; i < rem; ++i)
            acc += sex[i] * h2pre[(size_t)ssrc[i] * C2 + t];
    }
    float v = acc + b2[t];
    v = v > 0.f ? v : 0.f;
    int g = batch[d];
    atomicAdd(&pooled[g * C2 + t], v);
}

// ---------------- BN ----------------

__global__ __launch_bounds__(512) void k_bn(const float* __restrict__ pooled,
                                            const float* __restrict__ cnt,
                                            const float* __restrict__ gamma,
                                            const float* __restrict__ beta,
                                            float* __restrict__ out) {
    int c = blockIdx.x;
    int g = threadIdx.x;
    __shared__ float red[512];
    __shared__ float s_mu, s_var;
    float v = pooled[g * C2 + c] / fmaxf(cnt[g], 1.0f);
    red[g] = v;
    __syncthreads();
    for (int s = 256; s > 0; s >>= 1) {
        if (g < s) red[g] += red[g + s];
        __syncthreads();
    }
    if (g == 0) s_mu = red[0] * (1.0f / N_GRAPHS);
    __syncthreads();
    float dv = v - s_mu;
    red[g] = dv * dv;
    __syncthreads();
    for (int s = 256; s > 0; s >>= 1) {
        if (g < s) red[g] += red[g + s];
        __syncthreads();
    }
    if (g == 0) s_var = red[0] * (1.0f / N_GRAPHS);
    __syncthreads();
    out[g * C2 + c] = dv * rsqrtf(s_var + 1e-5f) * gamma[c] + beta[c];
}

extern "C" void kernel_launch(void* const* d_in, const int* in_sizes, int n_in,
                              void* d_out, int out_size, void* d_ws, size_t ws_size,
                              hipStream_t stream) {
    const float* x     = (const float*)d_in[0];
    const int*   eidx  = (const int*)d_in[1];
    const int*   batch = (const int*)d_in[2];
    const float* W1    = (const float*)d_in[3];
    const float* atts1 = (const float*)d_in[4];
    const float* attd1 = (const float*)d_in[5];
    const float* b1    = (const float*)d_in[6];
    const float* W2    = (const float*)d_in[7];
    const float* atts2 = (const float*)d_in[8];
    const float* attd2 = (const float*)d_in[9];
    const float* b2    = (const float*)d_in[10];
    const float* gamma = (const float*)d_in[11];
    const float* beta  = (const float*)d_in[12];
    float* out = (float*)d_out;
    float* ws  = (float*)d_ws;

    const int* src = eidx;
    const int* dst = eidx + N_EDGES;

    // workspace layout, element offsets (fp32/int32)
    const size_t o_h1pre  = 0;           // 12,800,000
    const size_t o_h1     = 12800000;    // 12,800,000
    const size_t o_h2pre  = 25600000;    // 6,400,000
    const size_t o_as1    = 32000000;    // 200,000
    const size_t o_ad1    = 32200000;    // 200,000
    const size_t o_as2    = 32400000;    // 50,000
    const size_t o_ad2    = 32450000;    // 50,000
    const size_t o_incl   = 32500000;    // 50,176 (padded)
    const size_t o_bsum   = 32550176;    // 256
    const size_t o_boff   = 32550432;    // 256
    const size_t o_rowptr = 32550688;    // 50,004
    const size_t o_csrc   = 32600692;    // 850,000
    // ---- contiguous zero block from here ----
    const size_t o_deg    = 33450692;    // 50,176
    const size_t o_cursor = 33500868;    // 50,000
    const size_t o_pool   = 33550868;    // 65,536
    const size_t o_cnt    = 33616404;    // 512
    const size_t total    = 33616916;    // ~134.5 MB

    int* p_incl   = (int*)(ws + o_incl);
    int* p_bsum   = (int*)(ws + o_bsum);
    int* p_boff   = (int*)(ws + o_boff);
    int* p_rowptr = (int*)(ws + o_rowptr);
    int* p_csrc   = (int*)(ws + o_csrc);
    int* p_deg    = (int*)(ws + o_deg);
    int* p_cursor = (int*)(ws + o_cursor);

    hipMemsetAsync(ws + o_deg, 0, (total - o_deg) * sizeof(float), stream);

    // ---- CSR build ----
    k_hist<<<(E_TOT + 255) / 256, 256, 0, stream>>>(src, dst, p_deg);
    k_scan1<<<NBLK, 256, 0, stream>>>(p_deg, p_incl, p_bsum);
    k_scan2<<<1, 256, 0, stream>>>(p_bsum, p_boff);
    k_scan3<<<NBLK, 256, 0, stream>>>(p_incl, p_boff, batch, p_rowptr, ws + o_cnt);
    k_scatter<<<(E_TOT + 255) / 256, 256, 0, stream>>>(src, dst, p_rowptr, p_cursor, p_csrc);

    // ---- layer 1 ----
    k_gemm1<<<(N_NODES + 63) / 64, 256, 0, stream>>>(x, W1, ws + o_h1pre);
    k_att1<<<N_NODES, 256, 0, stream>>>(ws + o_h1pre, atts1, attd1, ws + o_as1, ws + o_ad1);
    k_l1_agg<<<N_NODES, 256, 0, stream>>>(p_rowptr, p_csrc, ws + o_as1, ws + o_ad1,
                                          ws + o_h1pre, b1, ws + o_h1);

    // ---- layer 2 ----
    k_gemm2<<<(N_NODES + 127) / 128, 256, 0, stream>>>(ws + o_h1, W2, ws + o_h2pre);
    k_att2<<<(N_NODES + 3) / 4, 256, 0, stream>>>(ws + o_h2pre, atts2, attd2, ws + o_as2, ws + o_ad2);
    k_l2_aggpool<<<N_NODES, 128, 0, stream>>>(p_rowptr, p_csrc, ws + o_as2, ws + o_ad2,
                                              ws + o_h2pre, b2, batch, ws + o_pool);

    // ---- BN ----
    k_bn<<<C2, 512, 0, stream>>>(ws + o_pool, ws + o_cnt, gamma, beta, out);
}

// Round 5
// 541.415 us; speedup vs baseline: 3.5950x; 1.0272x over previous
//
#include <hip/hip_runtime.h>
#include <hip/hip_bf16.h>
#include <math.h>

#define N_NODES  50000
#define N_EDGES  800000
#define E_TOT    850000   // + self loops
#define N_GRAPHS 512
#define IN_CH    58
#define C1       256      // HEADS1 * H = 4*64
#define H1       4
#define C2       128
#define NEG_SLOPE 0.2f
#define NBLK     196      // ceil(50000/256) scan blocks

__device__ __forceinline__ float bf2f(unsigned short u) {
    return __uint_as_float((unsigned)u << 16);
}

// ---------------- CSR build ----------------

__global__ void k_hist(const int* __restrict__ src, const int* __restrict__ dst,
                       int* __restrict__ deg) {
    int j = blockIdx.x * blockDim.x + threadIdx.x;
    if (j >= E_TOT) return;
    int d = (j < N_EDGES) ? dst[j] : (j - N_EDGES);
    atomicAdd(&deg[d], 1);
}

__global__ __launch_bounds__(256) void k_scan1(const int* __restrict__ deg,
                                               int* __restrict__ incl,
                                               int* __restrict__ bsum) {
    __shared__ int sh[256];
    int t = threadIdx.x;
    int j = blockIdx.x * 256 + t;
    int v = (j < N_NODES) ? deg[j] : 0;
    sh[t] = v;
    __syncthreads();
    for (int o = 1; o < 256; o <<= 1) {
        int u = (t >= o) ? sh[t - o] : 0;
        __syncthreads();
        sh[t] += u;
        __syncthreads();
    }
    incl[j] = sh[t];                         // incl padded to 50176
    if (t == 255) bsum[blockIdx.x] = sh[255];
}

__global__ __launch_bounds__(256) void k_scan2(const int* __restrict__ bsum,
                                               int* __restrict__ boff) {
    __shared__ int sh[256];
    int t = threadIdx.x;
    int v = (t < NBLK) ? bsum[t] : 0;
    sh[t] = v;
    __syncthreads();
    for (int o = 1; o < 256; o <<= 1) {
        int u = (t >= o) ? sh[t - o] : 0;
        __syncthreads();
        sh[t] += u;
        __syncthreads();
    }
    boff[t] = sh[t] - v;                     // exclusive
}

__global__ __launch_bounds__(256) void k_scan3(const int* __restrict__ incl,
                                               const int* __restrict__ boff,
                                               const int* __restrict__ batch,
                                               int* __restrict__ row_ptr,
                                               float* __restrict__ cnt) {
    int j = blockIdx.x * 256 + threadIdx.x;
    if (j >= N_NODES) return;
    row_ptr[j + 1] = boff[blockIdx.x] + incl[j];
    if (j == 0) row_ptr[0] = 0;
    atomicAdd(&cnt[batch[j]], 1.0f);
}

__global__ void k_scatter(const int* __restrict__ src, const int* __restrict__ dst,
                          const int* __restrict__ row_ptr, int* __restrict__ cursor,
                          int* __restrict__ csrc) {
    int j = blockIdx.x * blockDim.x + threadIdx.x;
    if (j >= E_TOT) return;
    int s, d;
    if (j < N_EDGES) { s = src[j]; d = dst[j]; } else { s = d = j - N_EDGES; }
    int pos = atomicAdd(&cursor[d], 1);
    csrc[row_ptr[d] + pos] = s;
}

// ---------------- layer 1 GEMM (tiled, bf16 out, fused att logits) ----------------
// C tile 64 nodes x 256 ch; whole W1 in LDS; 8x8 per thread.
__global__ __launch_bounds__(256) void k_gemm1(const float* __restrict__ x,
                                               const float* __restrict__ W1,
                                               const float* __restrict__ atts,
                                               const float* __restrict__ attd,
                                               __hip_bfloat16* __restrict__ h1bf,
                                               float* __restrict__ a_s,
                                               float* __restrict__ a_d) {
    __shared__ float Xs[64][60];      // node-major, 58 padded to 60
    __shared__ float Ws[IN_CH][C1];
    int m0 = blockIdx.x * 64;
    int t = threadIdx.x;
    for (int idx = t; idx < 64 * IN_CH; idx += 256) {
        int m = idx / IN_CH, k = idx - m * IN_CH;
        int n = m0 + m;
        Xs[m][k] = (n < N_NODES) ? x[(size_t)n * IN_CH + k] : 0.f;
    }
    for (int idx = t * 4; idx < IN_CH * C1; idx += 1024)
        *(float4*)(&Ws[0][0] + idx) = *(const float4*)(W1 + idx);
    __syncthreads();
    int tr = t >> 5, tc = t & 31;     // nodes tr*8+i, channels tc+32*j
    float acc[8][8] = {{0.f}};
    for (int kk = 0; kk < IN_CH; ++kk) {
        float a[8], b[8];
#pragma unroll
        for (int i = 0; i < 8; ++i) a[i] = Xs[tr * 8 + i][kk];
#pragma unroll
        for (int j = 0; j < 8; ++j) b[j] = Ws[kk][tc + 32 * j];
#pragma unroll
        for (int i = 0; i < 8; ++i)
#pragma unroll
            for (int j = 0; j < 8; ++j) acc[i][j] += a[i] * b[j];
    }
    // att vectors for this thread's channels (j=2h -> ch tc+64h; j=2h+1 -> tc+32+64h)
    float ar[8], dr[8];
#pragma unroll
    for (int j = 0; j < 8; ++j) { ar[j] = atts[tc + 32 * j]; dr[j] = attd[tc + 32 * j]; }
#pragma unroll
    for (int i = 0; i < 8; ++i) {
        int n = m0 + tr * 8 + i;
        bool ok = n < N_NODES;
        if (ok) {
#pragma unroll
            for (int j = 0; j < 8; ++j)
                h1bf[(size_t)n * C1 + tc + 32 * j] = __float2bfloat16(acc[i][j]);
        }
#pragma unroll
        for (int h = 0; h < H1; ++h) {
            float ps = acc[i][2 * h] * ar[2 * h] + acc[i][2 * h + 1] * ar[2 * h + 1];
            float pd = acc[i][2 * h] * dr[2 * h] + acc[i][2 * h + 1] * dr[2 * h + 1];
#pragma unroll
            for (int o = 16; o > 0; o >>= 1) {
                ps += __shfl_down(ps, o, 32);
                pd += __shfl_down(pd, o, 32);
            }
            if (tc == 0 && ok) { a_s[n * H1 + h] = ps; a_d[n * H1 + h] = pd; }
        }
    }
}

// fused softmax + aggregate + bias + relu; bf16 gather, 4 ch/thread, 4 edges in flight
__global__ __launch_bounds__(256) void k_l1_agg(const int* __restrict__ row_ptr,
                                                const int* __restrict__ csrc,
                                                const float* __restrict__ a_s,
                                                const float* __restrict__ a_d,
                                                const __hip_bfloat16* __restrict__ h1bf,
                                                const float* __restrict__ b1,
                                                float* __restrict__ h1out) {
    int d = blockIdx.x;
    int t = threadIdx.x;
    int lane = t & 63, h = t >> 6;
    int beg = row_ptr[d];
    int deg = row_ptr[d + 1] - beg;
    float ad = a_d[d * H1 + h];

    // phase A: online softmax, wave h owns head h
    float m = -1e30f, z = 0.f;
    for (int i = lane; i < deg; i += 64) {
        int s = csrc[beg + i];
        float e = a_s[s * H1 + h] + ad;
        e = e > 0.f ? e : NEG_SLOPE * e;
        float M = fmaxf(m, e);
        z = z * __expf(m - M) + __expf(e - M);
        m = M;
    }
#pragma unroll
    for (int o = 32; o > 0; o >>= 1) {
        float m2 = __shfl_down(m, o, 64);
        float z2 = __shfl_down(z, o, 64);
        float M = fmaxf(m, m2);
        z = z * __expf(m - M) + z2 * __expf(m2 - M);
        m = M;
    }
    __shared__ float sm[H1], sinv[H1];
    if (lane == 0) { sm[h] = m; sinv[h] = 1.f / z; }
    __syncthreads();
    float mh = sm[h], invh = sinv[h];

    // phase B: quad q = channels 4q..4q+3 ; e = wave = edge slot
    __shared__ int   ssrc[64];
    __shared__ float sex[64][H1];
    int q = t & 63, e = t >> 6;
    int cq = q * 4;
    int hq = q >> 4;                  // head of this quad
    const unsigned short* hb = (const unsigned short*)h1bf;
    float acc0 = 0.f, acc1 = 0.f, acc2 = 0.f, acc3 = 0.f;
    for (int chunk = 0; chunk < deg; chunk += 64) {
        int rem = min(64, deg - chunk);
        __syncthreads();
        if (q < rem) {                // stage: thread (q, h) does edge q, head h
            int s = csrc[beg + chunk + q];
            if (h == 0) ssrc[q] = s;
            float el = a_s[s * H1 + h] + ad;
            el = el > 0.f ? el : NEG_SLOPE * el;
            sex[q][h] = __expf(el - mh) * invh;
        }
        __syncthreads();
        for (int i2 = 0; i2 < rem; i2 += 4) {
            int ie = i2 + e;          // wave-uniform
            if (ie < rem) {
                int s = ssrc[ie];
                float al = sex[ie][hq];
                ushort4 u = *(const ushort4*)(hb + (size_t)s * C1 + cq);
                acc0 += al * bf2f(u.x);
                acc1 += al * bf2f(u.y);
                acc2 += al * bf2f(u.z);
                acc3 += al * bf2f(u.w);
            }
        }
    }
    __shared__ float red[4][C1];
    *(float4*)(&red[e][cq]) = make_float4(acc0, acc1, acc2, acc3);
    __syncthreads();
    int c = t;
    float v = red[0][c] + red[1][c] + red[2][c] + red[3][c] + b1[c];
    h1out[(size_t)d * C1 + c] = v > 0.f ? v : 0.f;
}

// ---------------- layer 2 GEMM (tiled, bf16 out, fused att logits) ----------------
__global__ __launch_bounds__(256) void k_gemm2(const float* __restrict__ h1,
                                               const float* __restrict__ W2,
                                               const float* __restrict__ atts,
                                               const float* __restrict__ attd,
                                               __hip_bfloat16* __restrict__ h2bf,
                                               float* __restrict__ a_s,
                                               float* __restrict__ a_d) {
    __shared__ float As[128][68];
    __shared__ float Bs[64][C2];
    int m0 = blockIdx.x * 128;
    int t = threadIdx.x;
    int tr = t >> 4, tc = t & 15;     // nodes tr*8+i, channels tc+16*j
    float acc[8][8] = {{0.f}};
    for (int k0 = 0; k0 < C1; k0 += 64) {
        __syncthreads();
        {
            int mm  = t >> 4;
            int kk4 = (t & 15) * 4;
#pragma unroll
            for (int it = 0; it < 8; ++it) {
                int m = mm + 16 * it;
                int n = m0 + m;
                float4 v;
                if (n < N_NODES) v = *(const float4*)(h1 + (size_t)n * C1 + k0 + kk4);
                else             v = make_float4(0.f, 0.f, 0.f, 0.f);
                *(float4*)(&As[m][kk4]) = v;
            }
        }
        {
            int kB = t >> 5;
            int cB = (t & 31) * 4;
#pragma unroll
            for (int it = 0; it < 8; ++it) {
                int k = kB + 8 * it;
                *(float4*)(&Bs[k][cB]) = *(const float4*)(W2 + (size_t)(k0 + k) * C2 + cB);
            }
        }
        __syncthreads();
        for (int kk = 0; kk < 64; ++kk) {
            float a[8], b[8];
#pragma unroll
            for (int i = 0; i < 8; ++i) a[i] = As[tr * 8 + i][kk];
#pragma unroll
            for (int j = 0; j < 8; ++j) b[j] = Bs[kk][tc + 16 * j];
#pragma unroll
            for (int i = 0; i < 8; ++i)
#pragma unroll
                for (int j = 0; j < 8; ++j) acc[i][j] += a[i] * b[j];
        }
    }
    float ar[8], dr[8];
#pragma unroll
    for (int j = 0; j < 8; ++j) { ar[j] = atts[tc + 16 * j]; dr[j] = attd[tc + 16 * j]; }
#pragma unroll
    for (int i = 0; i < 8; ++i) {
        int n = m0 + tr * 8 + i;
        bool ok = n < N_NODES;
        if (ok) {
#pragma unroll
            for (int j = 0; j < 8; ++j)
                h2bf[(size_t)n * C2 + tc + 16 * j] = __float2bfloat16(acc[i][j]);
        }
        float ps = 0.f, pd = 0.f;
#pragma unroll
        for (int j = 0; j < 8; ++j) { ps += acc[i][j] * ar[j]; pd += acc[i][j] * dr[j]; }
#pragma unroll
        for (int o = 8; o > 0; o >>= 1) {
            ps += __shfl_down(ps, o, 16);
            pd += __shfl_down(pd, o, 16);
        }
        if (tc == 0 && ok) { a_s[n] = ps; a_d[n] = pd; }
    }
}

// fused softmax + aggregate + bias + relu + mean-pool; bf16 gather, 4 ch/thread, 8 edges
__global__ __launch_bounds__(256) void k_l2_aggpool(const int* __restrict__ row_ptr,
                                                    const int* __restrict__ csrc,
                                                    const float* __restrict__ a_s,
                                                    const float* __restrict__ a_d,
                                                    const __hip_bfloat16* __restrict__ h2bf,
                                                    const float* __restrict__ b2,
                                                    const int* __restrict__ batch,
                                                    float* __restrict__ pooled) {
    int d = blockIdx.x;
    int t = threadIdx.x;
    int lane = t & 63, w = t >> 6;
    int beg = row_ptr[d];
    int deg = row_ptr[d + 1] - beg;
    float ad = a_d[d];

    float m = -1e30f, z = 0.f;
    for (int i = t; i < deg; i += 256) {
        int s = csrc[beg + i];
        float e = a_s[s] + ad;
        e = e > 0.f ? e : NEG_SLOPE * e;
        float M = fmaxf(m, e);
        z = z * __expf(m - M) + __expf(e - M);
        m = M;
    }
#pragma unroll
    for (int o = 32; o > 0; o >>= 1) {
        float m2 = __shfl_down(m, o, 64);
        float z2 = __shfl_down(z, o, 64);
        float M = fmaxf(m, m2);
        z = z * __expf(m - M) + z2 * __expf(m2 - M);
        m = M;
    }
    __shared__ float rm[4], rz[4];
    __shared__ float smv, sinv;
    if (lane == 0) { rm[w] = m; rz[w] = z; }
    __syncthreads();
    if (t == 0) {
        float M = fmaxf(fmaxf(rm[0], rm[1]), fmaxf(rm[2], rm[3]));
        float Z = rz[0] * __expf(rm[0] - M) + rz[1] * __expf(rm[1] - M)
                + rz[2] * __expf(rm[2] - M) + rz[3] * __expf(rm[3] - M);
        smv = M; sinv = 1.f / Z;
    }
    __syncthreads();
    float mh = smv, invh = sinv;

    __shared__ int   ssrc[64];
    __shared__ float sex[64];
    int q = t & 31, e = t >> 5;        // channels 4q..4q+3 ; 8 edge slots
    int cq = q * 4;
    const unsigned short* hb = (const unsigned short*)h2bf;
    float acc0 = 0.f, acc1 = 0.f, acc2 = 0.f, acc3 = 0.f;
    for (int chunk = 0; chunk < deg; chunk += 64) {
        int rem = min(64, deg - chunk);
        __syncthreads();
        if (t < rem) {
            int s = csrc[beg + chunk + t];
            ssrc[t] = s;
            float el = a_s[s] + ad;
            el = el > 0.f ? el : NEG_SLOPE * el;
            sex[t] = __expf(el - mh) * invh;
        }
        __syncthreads();
        for (int i2 = 0; i2 < rem; i2 += 8) {
            int ie = i2 + e;
            if (ie < rem) {
                int s = ssrc[ie];
                float al = sex[ie];
                ushort4 u = *(const ushort4*)(hb + (size_t)s * C2 + cq);
                acc0 += al * bf2f(u.x);
                acc1 += al * bf2f(u.y);
                acc2 += al * bf2f(u.z);
                acc3 += al * bf2f(u.w);
            }
        }
    }
    __shared__ float red[8][C2];
    *(float4*)(&red[e][cq]) = make_float4(acc0, acc1, acc2, acc3);
    __syncthreads();
    if (t < C2) {
        float v = 0.f;
#pragma unroll
        for (int e2 = 0; e2 < 8; ++e2) v += red[e2][t];
        v += b2[t];
        v = v > 0.f ? v : 0.f;
        atomicAdd(&pooled[batch[d] * C2 + t], v);
    }
}

// ---------------- BN ----------------

__global__ __launch_bounds__(512) void k_bn(const float* __restrict__ pooled,
                                            const float* __restrict__ cnt,
                                            const float* __restrict__ gamma,
                                            const float* __restrict__ beta,
                                            float* __restrict__ out) {
    int c = blockIdx.x;
    int g = threadIdx.x;
    __shared__ float red[512];
    __shared__ float s_mu, s_var;
    float v = pooled[g * C2 + c] / fmaxf(cnt[g], 1.0f);
    red[g] = v;
    __syncthreads();
    for (int s = 256; s > 0; s >>= 1) {
        if (g < s) red[g] += red[g + s];
        __syncthreads();
    }
    if (g == 0) s_mu = red[0] * (1.0f / N_GRAPHS);
    __syncthreads();
    float dv = v - s_mu;
    red[g] = dv * dv;
    __syncthreads();
    for (int s = 256; s > 0; s >>= 1) {
        if (g < s) red[g] += red[g + s];
        __syncthreads();
    }
    if (g == 0) s_var = red[0] * (1.0f / N_GRAPHS);
    __syncthreads();
    out[g * C2 + c] = dv * rsqrtf(s_var + 1e-5f) * gamma[c] + beta[c];
}

extern "C" void kernel_launch(void* const* d_in, const int* in_sizes, int n_in,
                              void* d_out, int out_size, void* d_ws, size_t ws_size,
                              hipStream_t stream) {
    const float* x     = (const float*)d_in[0];
    const int*   eidx  = (const int*)d_in[1];
    const int*   batch = (const int*)d_in[2];
    const float* W1    = (const float*)d_in[3];
    const float* atts1 = (const float*)d_in[4];
    const float* attd1 = (const float*)d_in[5];
    const float* b1    = (const float*)d_in[6];
    const float* W2    = (const float*)d_in[7];
    const float* atts2 = (const float*)d_in[8];
    const float* attd2 = (const float*)d_in[9];
    const float* b2    = (const float*)d_in[10];
    const float* gamma = (const float*)d_in[11];
    const float* beta  = (const float*)d_in[12];
    float* out = (float*)d_out;
    float* ws  = (float*)d_ws;

    const int* src = eidx;
    const int* dst = eidx + N_EDGES;

    // workspace layout, float-element offsets
    const size_t o_h1bf   = 0;           // 12.8M bf16 = 6,400,000 floats
    const size_t o_h1     = 6400000;     // 12,800,000 fp32
    const size_t o_h2bf   = 19200000;    // 6.4M bf16 = 3,200,000 floats
    const size_t o_as1    = 22400000;    // 200,000
    const size_t o_ad1    = 22600000;    // 200,000
    const size_t o_as2    = 22800000;    // 50,000
    const size_t o_ad2    = 22850000;    // 50,000
    const size_t o_incl   = 22900000;    // 50,176 (padded)
    const size_t o_bsum   = 22950176;    // 256
    const size_t o_boff   = 22950432;    // 256
    const size_t o_rowptr = 22950688;    // 50,004
    const size_t o_csrc   = 23000692;    // 850,000
    // ---- contiguous zero block from here ----
    const size_t o_deg    = 23850692;    // 50,176
    const size_t o_cursor = 23900868;    // 50,000
    const size_t o_pool   = 23950868;    // 65,536
    const size_t o_cnt    = 24016404;    // 512
    const size_t total    = 24016916;    // ~96 MB

    int* p_incl   = (int*)(ws + o_incl);
    int* p_bsum   = (int*)(ws + o_bsum);
    int* p_boff   = (int*)(ws + o_boff);
    int* p_rowptr = (int*)(ws + o_rowptr);
    int* p_csrc   = (int*)(ws + o_csrc);
    int* p_deg    = (int*)(ws + o_deg);
    int* p_cursor = (int*)(ws + o_cursor);
    __hip_bfloat16* p_h1bf = (__hip_bfloat16*)(ws + o_h1bf);
    __hip_bfloat16* p_h2bf = (__hip_bfloat16*)(ws + o_h2bf);

    hipMemsetAsync(ws + o_deg, 0, (total - o_deg) * sizeof(float), stream);

    // ---- CSR build ----
    k_hist<<<(E_TOT + 255) / 256, 256, 0, stream>>>(src, dst, p_deg);
    k_scan1<<<NBLK, 256, 0, stream>>>(p_deg, p_incl, p_bsum);
    k_scan2<<<1, 256, 0, stream>>>(p_bsum, p_boff);
    k_scan3<<<NBLK, 256, 0, stream>>>(p_incl, p_boff, batch, p_rowptr, ws + o_cnt);
    k_scatter<<<(E_TOT + 255) / 256, 256, 0, stream>>>(src, dst, p_rowptr, p_cursor, p_csrc);

    // ---- layer 1 ----
    k_gemm1<<<(N_NODES + 63) / 64, 256, 0, stream>>>(x, W1, atts1, attd1,
                                                     p_h1bf, ws + o_as1, ws + o_ad1);
    k_l1_agg<<<N_NODES, 256, 0, stream>>>(p_rowptr, p_csrc, ws + o_as1, ws + o_ad1,
                                          p_h1bf, b1, ws + o_h1);

    // ---- layer 2 ----
    k_gemm2<<<(N_NODES + 127) / 128, 256, 0, stream>>>(ws + o_h1, W2, atts2, attd2,
                                                       p_h2bf, ws + o_as2, ws + o_ad2);
    k_l2_aggpool<<<N_NODES, 256, 0, stream>>>(p_rowptr, p_csrc, ws + o_as2, ws + o_ad2,
                                              p_h2bf, b2, batch, ws + o_pool);

    // ---- BN ----
    k_bn<<<C2, 512, 0, stream>>>(ws + o_pool, ws + o_cnt, gamma, beta, out);
}

// Round 6
// 497.803 us; speedup vs baseline: 3.9100x; 1.0876x over previous
//
#include <hip/hip_runtime.h>
#include <hip/hip_bf16.h>
#include <math.h>

#define N_NODES  50000
#define N_EDGES  800000
#define E_TOT    850000   // + self loops
#define N_GRAPHS 512
#define IN_CH    58
#define C1       256      // HEADS1 * H = 4*64
#define H1       4
#define C2       128
#define NEG_SLOPE 0.2f
#define NBLK     196      // ceil(50000/256) scan blocks

__device__ __forceinline__ float lo16(unsigned u) { return __uint_as_float(u << 16); }
__device__ __forceinline__ float hi16(unsigned u) { return __uint_as_float(u & 0xffff0000u); }
__device__ __forceinline__ float leaky(float e) { return e > 0.f ? e : NEG_SLOPE * e; }

// ---------------- CSR build ----------------

__global__ void k_hist(const int* __restrict__ src, const int* __restrict__ dst,
                       int* __restrict__ deg) {
    int j = blockIdx.x * blockDim.x + threadIdx.x;
    if (j >= E_TOT) return;
    int d = (j < N_EDGES) ? dst[j] : (j - N_EDGES);
    atomicAdd(&deg[d], 1);
}

__global__ __launch_bounds__(256) void k_scan1(const int* __restrict__ deg,
                                               int* __restrict__ incl,
                                               int* __restrict__ bsum) {
    __shared__ int sh[256];
    int t = threadIdx.x;
    int j = blockIdx.x * 256 + t;
    int v = (j < N_NODES) ? deg[j] : 0;
    sh[t] = v;
    __syncthreads();
    for (int o = 1; o < 256; o <<= 1) {
        int u = (t >= o) ? sh[t - o] : 0;
        __syncthreads();
        sh[t] += u;
        __syncthreads();
    }
    incl[j] = sh[t];
    if (t == 255) bsum[blockIdx.x] = sh[255];
}

__global__ __launch_bounds__(256) void k_scan2(const int* __restrict__ bsum,
                                               int* __restrict__ boff) {
    __shared__ int sh[256];
    int t = threadIdx.x;
    int v = (t < NBLK) ? bsum[t] : 0;
    sh[t] = v;
    __syncthreads();
    for (int o = 1; o < 256; o <<= 1) {
        int u = (t >= o) ? sh[t - o] : 0;
        __syncthreads();
        sh[t] += u;
        __syncthreads();
    }
    boff[t] = sh[t] - v;
}

__global__ __launch_bounds__(256) void k_scan3(const int* __restrict__ incl,
                                               const int* __restrict__ boff,
                                               const int* __restrict__ batch,
                                               int* __restrict__ row_ptr,
                                               float* __restrict__ cnt) {
    int j = blockIdx.x * 256 + threadIdx.x;
    if (j >= N_NODES) return;
    row_ptr[j + 1] = boff[blockIdx.x] + incl[j];
    if (j == 0) row_ptr[0] = 0;
    atomicAdd(&cnt[batch[j]], 1.0f);
}

__global__ void k_scatter(const int* __restrict__ src, const int* __restrict__ dst,
                          const int* __restrict__ row_ptr, int* __restrict__ cursor,
                          int* __restrict__ csrc) {
    int j = blockIdx.x * blockDim.x + threadIdx.x;
    if (j >= E_TOT) return;
    int s, d;
    if (j < N_EDGES) { s = src[j]; d = dst[j]; } else { s = d = j - N_EDGES; }
    int pos = atomicAdd(&cursor[d], 1);
    csrc[row_ptr[d] + pos] = s;
}

// ---------------- layer 1 GEMM (tiled, bf16 out, fused att logits) ----------------
__global__ __launch_bounds__(256) void k_gemm1(const float* __restrict__ x,
                                               const float* __restrict__ W1,
                                               const float* __restrict__ atts,
                                               const float* __restrict__ attd,
                                               __hip_bfloat16* __restrict__ h1bf,
                                               float* __restrict__ a_s,
                                               float* __restrict__ a_d) {
    __shared__ float Xs[64][60];
    __shared__ float Ws[IN_CH][C1];
    int m0 = blockIdx.x * 64;
    int t = threadIdx.x;
    for (int idx = t; idx < 64 * IN_CH; idx += 256) {
        int m = idx / IN_CH, k = idx - m * IN_CH;
        int n = m0 + m;
        Xs[m][k] = (n < N_NODES) ? x[(size_t)n * IN_CH + k] : 0.f;
    }
    for (int idx = t * 4; idx < IN_CH * C1; idx += 1024)
        *(float4*)(&Ws[0][0] + idx) = *(const float4*)(W1 + idx);
    __syncthreads();
    int tr = t >> 5, tc = t & 31;
    float acc[8][8] = {{0.f}};
    for (int kk = 0; kk < IN_CH; ++kk) {
        float a[8], b[8];
#pragma unroll
        for (int i = 0; i < 8; ++i) a[i] = Xs[tr * 8 + i][kk];
#pragma unroll
        for (int j = 0; j < 8; ++j) b[j] = Ws[kk][tc + 32 * j];
#pragma unroll
        for (int i = 0; i < 8; ++i)
#pragma unroll
            for (int j = 0; j < 8; ++j) acc[i][j] += a[i] * b[j];
    }
    float ar[8], dr[8];
#pragma unroll
    for (int j = 0; j < 8; ++j) { ar[j] = atts[tc + 32 * j]; dr[j] = attd[tc + 32 * j]; }
#pragma unroll
    for (int i = 0; i < 8; ++i) {
        int n = m0 + tr * 8 + i;
        bool ok = n < N_NODES;
        if (ok) {
#pragma unroll
            for (int j = 0; j < 8; ++j)
                h1bf[(size_t)n * C1 + tc + 32 * j] = __float2bfloat16(acc[i][j]);
        }
#pragma unroll
        for (int h = 0; h < H1; ++h) {
            float ps = acc[i][2 * h] * ar[2 * h] + acc[i][2 * h + 1] * ar[2 * h + 1];
            float pd = acc[i][2 * h] * dr[2 * h] + acc[i][2 * h + 1] * dr[2 * h + 1];
#pragma unroll
            for (int o = 16; o > 0; o >>= 1) {
                ps += __shfl_down(ps, o, 32);
                pd += __shfl_down(pd, o, 32);
            }
            if (tc == 0 && ok) { a_s[n * H1 + h] = ps; a_d[n * H1 + h] = pd; }
        }
    }
}

// ---------------- alpha kernels (one wave per dst node, no LDS/barriers) ----------------

__global__ __launch_bounds__(256) void k_alpha1(const int* __restrict__ row_ptr,
                                                const int* __restrict__ csrc,
                                                const float* __restrict__ a_s,
                                                const float* __restrict__ a_d,
                                                float* __restrict__ alpha) {
    int t = threadIdx.x;
    int d = blockIdx.x * 4 + (t >> 6);
    if (d >= N_NODES) return;
    int lane = t & 63;
    int beg = row_ptr[d], deg = row_ptr[d + 1] - beg;
    float4 ad = *(const float4*)(a_d + d * 4);
    float m0 = -1e30f, m1 = -1e30f, m2 = -1e30f, m3 = -1e30f;
    float z0 = 0.f, z1 = 0.f, z2 = 0.f, z3 = 0.f;
    for (int i = lane; i < deg; i += 64) {
        int s = csrc[beg + i];
        float4 as = *(const float4*)(a_s + s * 4);
        float e0 = leaky(as.x + ad.x), e1 = leaky(as.y + ad.y);
        float e2 = leaky(as.z + ad.z), e3 = leaky(as.w + ad.w);
        float M;
        M = fmaxf(m0, e0); z0 = z0 * __expf(m0 - M) + __expf(e0 - M); m0 = M;
        M = fmaxf(m1, e1); z1 = z1 * __expf(m1 - M) + __expf(e1 - M); m1 = M;
        M = fmaxf(m2, e2); z2 = z2 * __expf(m2 - M) + __expf(e2 - M); m2 = M;
        M = fmaxf(m3, e3); z3 = z3 * __expf(m3 - M) + __expf(e3 - M); m3 = M;
    }
#pragma unroll
    for (int o = 1; o < 64; o <<= 1) {
        float mm, zz, M;
        mm = __shfl_xor(m0, o, 64); zz = __shfl_xor(z0, o, 64);
        M = fmaxf(m0, mm); z0 = z0 * __expf(m0 - M) + zz * __expf(mm - M); m0 = M;
        mm = __shfl_xor(m1, o, 64); zz = __shfl_xor(z1, o, 64);
        M = fmaxf(m1, mm); z1 = z1 * __expf(m1 - M) + zz * __expf(mm - M); m1 = M;
        mm = __shfl_xor(m2, o, 64); zz = __shfl_xor(z2, o, 64);
        M = fmaxf(m2, mm); z2 = z2 * __expf(m2 - M) + zz * __expf(mm - M); m2 = M;
        mm = __shfl_xor(m3, o, 64); zz = __shfl_xor(z3, o, 64);
        M = fmaxf(m3, mm); z3 = z3 * __expf(m3 - M) + zz * __expf(mm - M); m3 = M;
    }
    float i0 = 1.f / z0, i1 = 1.f / z1, i2 = 1.f / z2, i3 = 1.f / z3;
    for (int i = lane; i < deg; i += 64) {
        int s = csrc[beg + i];
        float4 as = *(const float4*)(a_s + s * 4);
        float4 al;
        al.x = __expf(leaky(as.x + ad.x) - m0) * i0;
        al.y = __expf(leaky(as.y + ad.y) - m1) * i1;
        al.z = __expf(leaky(as.z + ad.z) - m2) * i2;
        al.w = __expf(leaky(as.w + ad.w) - m3) * i3;
        *(float4*)(alpha + (beg + i) * 4) = al;
    }
}

__global__ __launch_bounds__(256) void k_alpha2(const int* __restrict__ row_ptr,
                                                const int* __restrict__ csrc,
                                                const float* __restrict__ a_s,
                                                const float* __restrict__ a_d,
                                                float* __restrict__ alpha) {
    int t = threadIdx.x;
    int d = blockIdx.x * 4 + (t >> 6);
    if (d >= N_NODES) return;
    int lane = t & 63;
    int beg = row_ptr[d], deg = row_ptr[d + 1] - beg;
    float ad = a_d[d];
    float m = -1e30f, z = 0.f;
    for (int i = lane; i < deg; i += 64) {
        int s = csrc[beg + i];
        float e = leaky(a_s[s] + ad);
        float M = fmaxf(m, e);
        z = z * __expf(m - M) + __expf(e - M);
        m = M;
    }
#pragma unroll
    for (int o = 1; o < 64; o <<= 1) {
        float mm = __shfl_xor(m, o, 64), zz = __shfl_xor(z, o, 64);
        float M = fmaxf(m, mm);
        z = z * __expf(m - M) + zz * __expf(mm - M);
        m = M;
    }
    float iz = 1.f / z;
    for (int i = lane; i < deg; i += 64) {
        int s = csrc[beg + i];
        alpha[beg + i] = __expf(leaky(a_s[s] + ad) - m) * iz;
    }
}

// ---------------- layer 1 aggregate (one wave per node, barrier-free) ----------------
__global__ __launch_bounds__(256) void k_l1_agg(const int* __restrict__ row_ptr,
                                                const int* __restrict__ csrc,
                                                const float* __restrict__ alpha,
                                                const __hip_bfloat16* __restrict__ h1bf,
                                                const float* __restrict__ b1,
                                                float* __restrict__ h1out) {
    int t = threadIdx.x;
    int d = blockIdx.x * 4 + (t >> 6);
    if (d >= N_NODES) return;
    int lane = t & 63;
    int beg = row_ptr[d], deg = row_ptr[d + 1] - beg;
    int hq = lane >> 4;                       // head of my channel quad
    const uint2* rows = (const uint2*)h1bf;   // 64 uint2 per row (256 bf16)
    float a0 = 0.f, a1 = 0.f, a2 = 0.f, a3 = 0.f;
    int i = 0;
    for (; i + 4 <= deg; i += 4) {
        int e0 = beg + i;
        int s0 = csrc[e0], s1 = csrc[e0 + 1], s2 = csrc[e0 + 2], s3 = csrc[e0 + 3];
        float l0 = alpha[e0 * 4 + hq];
        float l1 = alpha[e0 * 4 + 4 + hq];
        float l2 = alpha[e0 * 4 + 8 + hq];
        float l3 = alpha[e0 * 4 + 12 + hq];
        uint2 u0 = rows[s0 * 64 + lane];
        uint2 u1 = rows[s1 * 64 + lane];
        uint2 u2 = rows[s2 * 64 + lane];
        uint2 u3 = rows[s3 * 64 + lane];
        a0 += l0 * lo16(u0.x); a1 += l0 * hi16(u0.x); a2 += l0 * lo16(u0.y); a3 += l0 * hi16(u0.y);
        a0 += l1 * lo16(u1.x); a1 += l1 * hi16(u1.x); a2 += l1 * lo16(u1.y); a3 += l1 * hi16(u1.y);
        a0 += l2 * lo16(u2.x); a1 += l2 * hi16(u2.x); a2 += l2 * lo16(u2.y); a3 += l2 * hi16(u2.y);
        a0 += l3 * lo16(u3.x); a1 += l3 * hi16(u3.x); a2 += l3 * lo16(u3.y); a3 += l3 * hi16(u3.y);
    }
    for (; i < deg; ++i) {
        int s = csrc[beg + i];
        float l = alpha[(beg + i) * 4 + hq];
        uint2 u = rows[s * 64 + lane];
        a0 += l * lo16(u.x); a1 += l * hi16(u.x); a2 += l * lo16(u.y); a3 += l * hi16(u.y);
    }
    int c = lane * 4;
    float4 bv = *(const float4*)(b1 + c);
    float4 o;
    o.x = a0 + bv.x; o.y = a1 + bv.y; o.z = a2 + bv.z; o.w = a3 + bv.w;
    o.x = o.x > 0.f ? o.x : 0.f;
    o.y = o.y > 0.f ? o.y : 0.f;
    o.z = o.z > 0.f ? o.z : 0.f;
    o.w = o.w > 0.f ? o.w : 0.f;
    *(float4*)(h1out + d * C1 + c) = o;
}

// ---------------- layer 2 GEMM (tiled, bf16 out, fused att logits) ----------------
__global__ __launch_bounds__(256) void k_gemm2(const float* __restrict__ h1,
                                               const float* __restrict__ W2,
                                               const float* __restrict__ atts,
                                               const float* __restrict__ attd,
                                               __hip_bfloat16* __restrict__ h2bf,
                                               float* __restrict__ a_s,
                                               float* __restrict__ a_d) {
    __shared__ float As[128][68];
    __shared__ float Bs[64][C2];
    int m0 = blockIdx.x * 128;
    int t = threadIdx.x;
    int tr = t >> 4, tc = t & 15;
    float acc[8][8] = {{0.f}};
    for (int k0 = 0; k0 < C1; k0 += 64) {
        __syncthreads();
        {
            int mm  = t >> 4;
            int kk4 = (t & 15) * 4;
#pragma unroll
            for (int it = 0; it < 8; ++it) {
                int m = mm + 16 * it;
                int n = m0 + m;
                float4 v;
                if (n < N_NODES) v = *(const float4*)(h1 + (size_t)n * C1 + k0 + kk4);
                else             v = make_float4(0.f, 0.f, 0.f, 0.f);
                *(float4*)(&As[m][kk4]) = v;
            }
        }
        {
            int kB = t >> 5;
            int cB = (t & 31) * 4;
#pragma unroll
            for (int it = 0; it < 8; ++it) {
                int k = kB + 8 * it;
                *(float4*)(&Bs[k][cB]) = *(const float4*)(W2 + (size_t)(k0 + k) * C2 + cB);
            }
        }
        __syncthreads();
        for (int kk = 0; kk < 64; ++kk) {
            float a[8], b[8];
#pragma unroll
            for (int i = 0; i < 8; ++i) a[i] = As[tr * 8 + i][kk];
#pragma unroll
            for (int j = 0; j < 8; ++j) b[j] = Bs[kk][tc + 16 * j];
#pragma unroll
            for (int i = 0; i < 8; ++i)
#pragma unroll
                for (int j = 0; j < 8; ++j) acc[i][j] += a[i] * b[j];
        }
    }
    float ar[8], dr[8];
#pragma unroll
    for (int j = 0; j < 8; ++j) { ar[j] = atts[tc + 16 * j]; dr[j] = attd[tc + 16 * j]; }
#pragma unroll
    for (int i = 0; i < 8; ++i) {
        int n = m0 + tr * 8 + i;
        bool ok = n < N_NODES;
        if (ok) {
#pragma unroll
            for (int j = 0; j < 8; ++j)
                h2bf[(size_t)n * C2 + tc + 16 * j] = __float2bfloat16(acc[i][j]);
        }
        float ps = 0.f, pd = 0.f;
#pragma unroll
        for (int j = 0; j < 8; ++j) { ps += acc[i][j] * ar[j]; pd += acc[i][j] * dr[j]; }
#pragma unroll
        for (int o = 8; o > 0; o >>= 1) {
            ps += __shfl_down(ps, o, 16);
            pd += __shfl_down(pd, o, 16);
        }
        if (tc == 0 && ok) { a_s[n] = ps; a_d[n] = pd; }
    }
}

// ---------------- layer 2 aggregate + pool (one wave per node) ----------------
__global__ __launch_bounds__(256) void k_l2_aggpool(const int* __restrict__ row_ptr,
                                                    const int* __restrict__ csrc,
                                                    const float* __restrict__ alpha,
                                                    const __hip_bfloat16* __restrict__ h2bf,
                                                    const float* __restrict__ b2,
                                                    const int* __restrict__ batch,
                                                    float* __restrict__ pooled) {
    int t = threadIdx.x;
    int d = blockIdx.x * 4 + (t >> 6);
    if (d >= N_NODES) return;
    int lane = t & 63;
    int beg = row_ptr[d], deg = row_ptr[d + 1] - beg;
    const unsigned* rows = (const unsigned*)h2bf;   // 64 uints per row (128 bf16)
    float a0 = 0.f, a1 = 0.f;
    int i = 0;
    for (; i + 8 <= deg; i += 8) {
        int e0 = beg + i;
        int s0 = csrc[e0], s1 = csrc[e0 + 1], s2 = csrc[e0 + 2], s3 = csrc[e0 + 3];
        int s4 = csrc[e0 + 4], s5 = csrc[e0 + 5], s6 = csrc[e0 + 6], s7 = csrc[e0 + 7];
        float l0 = alpha[e0], l1 = alpha[e0 + 1], l2 = alpha[e0 + 2], l3 = alpha[e0 + 3];
        float l4 = alpha[e0 + 4], l5 = alpha[e0 + 5], l6 = alpha[e0 + 6], l7 = alpha[e0 + 7];
        unsigned u0 = rows[s0 * 64 + lane], u1 = rows[s1 * 64 + lane];
        unsigned u2 = rows[s2 * 64 + lane], u3 = rows[s3 * 64 + lane];
        unsigned u4 = rows[s4 * 64 + lane], u5 = rows[s5 * 64 + lane];
        unsigned u6 = rows[s6 * 64 + lane], u7 = rows[s7 * 64 + lane];
        a0 += l0 * lo16(u0); a1 += l0 * hi16(u0);
        a0 += l1 * lo16(u1); a1 += l1 * hi16(u1);
        a0 += l2 * lo16(u2); a1 += l2 * hi16(u2);
        a0 += l3 * lo16(u3); a1 += l3 * hi16(u3);
        a0 += l4 * lo16(u4); a1 += l4 * hi16(u4);
        a0 += l5 * lo16(u5); a1 += l5 * hi16(u5);
        a0 += l6 * lo16(u6); a1 += l6 * hi16(u6);
        a0 += l7 * lo16(u7); a1 += l7 * hi16(u7);
    }
    for (; i < deg; ++i) {
        int s = csrc[beg + i];
        float l = alpha[beg + i];
        unsigned u = rows[s * 64 + lane];
        a0 += l * lo16(u); a1 += l * hi16(u);
    }
    int c = lane * 2;
    float v0 = a0 + b2[c], v1 = a1 + b2[c + 1];
    v0 = v0 > 0.f ? v0 : 0.f;
    v1 = v1 > 0.f ? v1 : 0.f;
    int g = batch[d];
    atomicAdd(&pooled[g * C2 + c], v0);
    atomicAdd(&pooled[g * C2 + c + 1], v1);
}

// ---------------- BN ----------------

__global__ __launch_bounds__(512) void k_bn(const float* __restrict__ pooled,
                                            const float* __restrict__ cnt,
                                            const float* __restrict__ gamma,
                                            const float* __restrict__ beta,
                                            float* __restrict__ out) {
    int c = blockIdx.x;
    int g = threadIdx.x;
    __shared__ float red[512];
    __shared__ float s_mu, s_var;
    float v = pooled[g * C2 + c] / fmaxf(cnt[g], 1.0f);
    red[g] = v;
    __syncthreads();
    for (int s = 256; s > 0; s >>= 1) {
        if (g < s) red[g] += red[g + s];
        __syncthreads();
    }
    if (g == 0) s_mu = red[0] * (1.0f / N_GRAPHS);
    __syncthreads();
    float dv = v - s_mu;
    red[g] = dv * dv;
    __syncthreads();
    for (int s = 256; s > 0; s >>= 1) {
        if (g < s) red[g] += red[g + s];
        __syncthreads();
    }
    if (g == 0) s_var = red[0] * (1.0f / N_GRAPHS);
    __syncthreads();
    out[g * C2 + c] = dv * rsqrtf(s_var + 1e-5f) * gamma[c] + beta[c];
}

extern "C" void kernel_launch(void* const* d_in, const int* in_sizes, int n_in,
                              void* d_out, int out_size, void* d_ws, size_t ws_size,
                              hipStream_t stream) {
    const float* x     = (const float*)d_in[0];
    const int*   eidx  = (const int*)d_in[1];
    const int*   batch = (const int*)d_in[2];
    const float* W1    = (const float*)d_in[3];
    const float* atts1 = (const float*)d_in[4];
    const float* attd1 = (const float*)d_in[5];
    const float* b1    = (const float*)d_in[6];
    const float* W2    = (const float*)d_in[7];
    const float* atts2 = (const float*)d_in[8];
    const float* attd2 = (const float*)d_in[9];
    const float* b2    = (const float*)d_in[10];
    const float* gamma = (const float*)d_in[11];
    const float* beta  = (const float*)d_in[12];
    float* out = (float*)d_out;
    float* ws  = (float*)d_ws;

    const int* src = eidx;
    const int* dst = eidx + N_EDGES;

    // workspace layout, float-element offsets
    const size_t o_h1bf   = 0;           // 12.8M bf16 = 6,400,000 floats
    const size_t o_h1     = 6400000;     // 12,800,000 fp32
    const size_t o_h2bf   = 19200000;    // 6.4M bf16 = 3,200,000 floats
    const size_t o_as1    = 22400000;    // 200,000
    const size_t o_ad1    = 22600000;    // 200,000
    const size_t o_as2    = 22800000;    // 50,000
    const size_t o_ad2    = 22850000;    // 50,000
    const size_t o_incl   = 22900000;    // 50,176 (padded)
    const size_t o_bsum   = 22950176;    // 256
    const size_t o_boff   = 22950432;    // 256
    const size_t o_rowptr = 22950688;    // 50,004
    const size_t o_csrc   = 23000692;    // 850,000
    const size_t o_alpha1 = 23850692;    // 3,400,000 (16B-aligned: offset %4 == 0)
    const size_t o_alpha2 = 27250692;    // 850,000
    // ---- contiguous zero block from here ----
    const size_t o_deg    = 28100692;    // 50,176
    const size_t o_cursor = 28150868;    // 50,000
    const size_t o_pool   = 28200868;    // 65,536
    const size_t o_cnt    = 28266404;    // 512
    const size_t total    = 28266916;    // ~113 MB

    int* p_incl   = (int*)(ws + o_incl);
    int* p_bsum   = (int*)(ws + o_bsum);
    int* p_boff   = (int*)(ws + o_boff);
    int* p_rowptr = (int*)(ws + o_rowptr);
    int* p_csrc   = (int*)(ws + o_csrc);
    int* p_deg    = (int*)(ws + o_deg);
    int* p_cursor = (int*)(ws + o_cursor);
    __hip_bfloat16* p_h1bf = (__hip_bfloat16*)(ws + o_h1bf);
    __hip_bfloat16* p_h2bf = (__hip_bfloat16*)(ws + o_h2bf);

    hipMemsetAsync(ws + o_deg, 0, (total - o_deg) * sizeof(float), stream);

    // ---- CSR build ----
    k_hist<<<(E_TOT + 255) / 256, 256, 0, stream>>>(src, dst, p_deg);
    k_scan1<<<NBLK, 256, 0, stream>>>(p_deg, p_incl, p_bsum);
    k_scan2<<<1, 256, 0, stream>>>(p_bsum, p_boff);
    k_scan3<<<NBLK, 256, 0, stream>>>(p_incl, p_boff, batch, p_rowptr, ws + o_cnt);
    k_scatter<<<(E_TOT + 255) / 256, 256, 0, stream>>>(src, dst, p_rowptr, p_cursor, p_csrc);

    const int nwb = (N_NODES + 3) / 4;   // 4 independent waves per 256-block

    // ---- layer 1 ----
    k_gemm1<<<(N_NODES + 63) / 64, 256, 0, stream>>>(x, W1, atts1, attd1,
                                                     p_h1bf, ws + o_as1, ws + o_ad1);
    k_alpha1<<<nwb, 256, 0, stream>>>(p_rowptr, p_csrc, ws + o_as1, ws + o_ad1, ws + o_alpha1);
    k_l1_agg<<<nwb, 256, 0, stream>>>(p_rowptr, p_csrc, ws + o_alpha1, p_h1bf, b1, ws + o_h1);

    // ---- layer 2 ----
    k_gemm2<<<(N_NODES + 127) / 128, 256, 0, stream>>>(ws + o_h1, W2, atts2, attd2,
                                                       p_h2bf, ws + o_as2, ws + o_ad2);
    k_alpha2<<<nwb, 256, 0, stream>>>(p_rowptr, p_csrc, ws + o_as2, ws + o_ad2, ws + o_alpha2);
    k_l2_aggpool<<<nwb, 256, 0, stream>>>(p_rowptr, p_csrc, ws + o_alpha2,
                                          p_h2bf, b2, batch, ws + o_pool);

    // ---- BN ----
    k_bn<<<C2, 512, 0, stream>>>(ws + o_pool, ws + o_cnt, gamma, beta, out);
}

// Round 7
// 431.404 us; speedup vs baseline: 4.5118x; 1.1539x over previous
//
#include <hip/hip_runtime.h>
#include <hip/hip_bf16.h>
#include <math.h>

#define N_NODES  50000
#define N_EDGES  800000
#define E_TOT    850000   // + self loops
#define N_GRAPHS 512
#define IN_CH    58
#define C1       256      // HEADS1 * H = 4*64
#define H1       4
#define C2       128
#define NEG_SLOPE 0.2f
#define NBLK     196      // ceil(50000/256) scan blocks

typedef __attribute__((ext_vector_type(8))) short short8;
typedef __attribute__((ext_vector_type(4))) float f32x4;

__device__ __forceinline__ float lo16(unsigned u) { return __uint_as_float(u << 16); }
__device__ __forceinline__ float hi16(unsigned u) { return __uint_as_float(u & 0xffff0000u); }
__device__ __forceinline__ float leaky(float e) { return e > 0.f ? e : NEG_SLOPE * e; }
__device__ __forceinline__ unsigned short f2bfu(float v) {
    __hip_bfloat16 b = __float2bfloat16(v);
    return *(unsigned short*)&b;
}

// ---------------- CSR build ----------------

__global__ void k_hist(const int* __restrict__ src, const int* __restrict__ dst,
                       int* __restrict__ deg) {
    int j = blockIdx.x * blockDim.x + threadIdx.x;
    if (j >= E_TOT) return;
    int d = (j < N_EDGES) ? dst[j] : (j - N_EDGES);
    atomicAdd(&deg[d], 1);
}

__global__ __launch_bounds__(256) void k_scan1(const int* __restrict__ deg,
                                               int* __restrict__ incl,
                                               int* __restrict__ bsum) {
    __shared__ int sh[256];
    int t = threadIdx.x;
    int j = blockIdx.x * 256 + t;
    int v = (j < N_NODES) ? deg[j] : 0;
    sh[t] = v;
    __syncthreads();
    for (int o = 1; o < 256; o <<= 1) {
        int u = (t >= o) ? sh[t - o] : 0;
        __syncthreads();
        sh[t] += u;
        __syncthreads();
    }
    incl[j] = sh[t];
    if (t == 255) bsum[blockIdx.x] = sh[255];
}

__global__ __launch_bounds__(256) void k_scan2(const int* __restrict__ bsum,
                                               int* __restrict__ boff) {
    __shared__ int sh[256];
    int t = threadIdx.x;
    int v = (t < NBLK) ? bsum[t] : 0;
    sh[t] = v;
    __syncthreads();
    for (int o = 1; o < 256; o <<= 1) {
        int u = (t >= o) ? sh[t - o] : 0;
        __syncthreads();
        sh[t] += u;
        __syncthreads();
    }
    boff[t] = sh[t] - v;
}

__global__ __launch_bounds__(256) void k_scan3(const int* __restrict__ incl,
                                               const int* __restrict__ boff,
                                               const int* __restrict__ batch,
                                               int* __restrict__ row_ptr,
                                               float* __restrict__ cnt) {
    int j = blockIdx.x * 256 + threadIdx.x;
    if (j >= N_NODES) return;
    row_ptr[j + 1] = boff[blockIdx.x] + incl[j];
    if (j == 0) row_ptr[0] = 0;
    atomicAdd(&cnt[batch[j]], 1.0f);
}

__global__ void k_scatter(const int* __restrict__ src, const int* __restrict__ dst,
                          const int* __restrict__ row_ptr, int* __restrict__ cursor,
                          int* __restrict__ csrc) {
    int j = blockIdx.x * blockDim.x + threadIdx.x;
    if (j >= E_TOT) return;
    int s, d;
    if (j < N_EDGES) { s = src[j]; d = dst[j]; } else { s = d = j - N_EDGES; }
    int pos = atomicAdd(&cursor[d], 1);
    csrc[row_ptr[d] + pos] = s;
}

// W2p[n][k] = bf16(W2[k][n])  (N-major, K-contiguous for MFMA B-frags)
__global__ __launch_bounds__(256) void k_prepw(const float* __restrict__ W2,
                                               __hip_bfloat16* __restrict__ w2p) {
    int n = blockIdx.x;
    int k = threadIdx.x;
    w2p[n * 256 + k] = __float2bfloat16(W2[k * 128 + n]);
}

// ---------------- layer 1 GEMM (tiled fp32, bf16 out, fused att logits) ----------------
__global__ __launch_bounds__(256) void k_gemm1(const float* __restrict__ x,
                                               const float* __restrict__ W1,
                                               const float* __restrict__ atts,
                                               const float* __restrict__ attd,
                                               __hip_bfloat16* __restrict__ h1bf,
                                               float* __restrict__ a_s,
                                               float* __restrict__ a_d) {
    __shared__ float Xs[64][60];
    __shared__ float Ws[IN_CH][C1];
    int m0 = blockIdx.x * 64;
    int t = threadIdx.x;
    for (int idx = t; idx < 64 * IN_CH; idx += 256) {
        int m = idx / IN_CH, k = idx - m * IN_CH;
        int n = m0 + m;
        Xs[m][k] = (n < N_NODES) ? x[(size_t)n * IN_CH + k] : 0.f;
    }
    for (int idx = t * 4; idx < IN_CH * C1; idx += 1024)
        *(float4*)(&Ws[0][0] + idx) = *(const float4*)(W1 + idx);
    __syncthreads();
    int tr = t >> 5, tc = t & 31;
    float acc[8][8] = {{0.f}};
    for (int kk = 0; kk < IN_CH; ++kk) {
        float a[8], b[8];
#pragma unroll
        for (int i = 0; i < 8; ++i) a[i] = Xs[tr * 8 + i][kk];
#pragma unroll
        for (int j = 0; j < 8; ++j) b[j] = Ws[kk][tc + 32 * j];
#pragma unroll
        for (int i = 0; i < 8; ++i)
#pragma unroll
            for (int j = 0; j < 8; ++j) acc[i][j] += a[i] * b[j];
    }
    float ar[8], dr[8];
#pragma unroll
    for (int j = 0; j < 8; ++j) { ar[j] = atts[tc + 32 * j]; dr[j] = attd[tc + 32 * j]; }
#pragma unroll
    for (int i = 0; i < 8; ++i) {
        int n = m0 + tr * 8 + i;
        bool ok = n < N_NODES;
        if (ok) {
#pragma unroll
            for (int j = 0; j < 8; ++j)
                h1bf[(size_t)n * C1 + tc + 32 * j] = __float2bfloat16(acc[i][j]);
        }
#pragma unroll
        for (int h = 0; h < H1; ++h) {
            float ps = acc[i][2 * h] * ar[2 * h] + acc[i][2 * h + 1] * ar[2 * h + 1];
            float pd = acc[i][2 * h] * dr[2 * h] + acc[i][2 * h + 1] * dr[2 * h + 1];
#pragma unroll
            for (int o = 16; o > 0; o >>= 1) {
                ps += __shfl_down(ps, o, 32);
                pd += __shfl_down(pd, o, 32);
            }
            if (tc == 0 && ok) { a_s[n * H1 + h] = ps; a_d[n * H1 + h] = pd; }
        }
    }
}

// ---------------- layer 1 aggregate: fused softmax (no max) + bias + relu, bf16 out ----
__global__ __launch_bounds__(256) void k_l1_agg(const int* __restrict__ row_ptr,
                                                const int* __restrict__ csrc,
                                                const float* __restrict__ a_s,
                                                const float* __restrict__ a_d,
                                                const __hip_bfloat16* __restrict__ h1bf,
                                                const float* __restrict__ b1,
                                                unsigned short* __restrict__ h1o) {
    int t = threadIdx.x;
    int d = blockIdx.x * 4 + (t >> 6);
    if (d >= N_NODES) return;
    int lane = t & 63;
    int beg = row_ptr[d], deg = row_ptr[d + 1] - beg;
    int hq = lane >> 4;
    float ad = a_d[d * 4 + hq];
    const uint2* rows = (const uint2*)h1bf;
    float a0 = 0.f, a1 = 0.f, a2 = 0.f, a3 = 0.f, z = 0.f;
    int i = 0;
    for (; i + 8 <= deg; i += 8) {
        int e0 = beg + i;
        int s[8]; uint2 u[8]; float ex[8];
#pragma unroll
        for (int k = 0; k < 8; ++k) s[k] = csrc[e0 + k];
#pragma unroll
        for (int k = 0; k < 8; ++k) u[k] = rows[s[k] * 64 + lane];
#pragma unroll
        for (int k = 0; k < 8; ++k) ex[k] = __expf(leaky(a_s[s[k] * 4 + hq] + ad));
#pragma unroll
        for (int k = 0; k < 8; ++k) {
            z  += ex[k];
            a0 += ex[k] * lo16(u[k].x); a1 += ex[k] * hi16(u[k].x);
            a2 += ex[k] * lo16(u[k].y); a3 += ex[k] * hi16(u[k].y);
        }
    }
    for (; i < deg; ++i) {
        int s = csrc[beg + i];
        uint2 u = rows[s * 64 + lane];
        float ex = __expf(leaky(a_s[s * 4 + hq] + ad));
        z  += ex;
        a0 += ex * lo16(u.x); a1 += ex * hi16(u.x);
        a2 += ex * lo16(u.y); a3 += ex * hi16(u.y);
    }
    float inv = 1.f / z;
    int c = lane * 4;
    float4 bv = *(const float4*)(b1 + c);
    float v0 = fmaxf(a0 * inv + bv.x, 0.f);
    float v1 = fmaxf(a1 * inv + bv.y, 0.f);
    float v2 = fmaxf(a2 * inv + bv.z, 0.f);
    float v3 = fmaxf(a3 * inv + bv.w, 0.f);
    ushort4 o;
    o.x = f2bfu(v0); o.y = f2bfu(v1); o.z = f2bfu(v2); o.w = f2bfu(v3);
    *(ushort4*)(h1o + d * C1 + c) = o;
}

// ---------------- layer 2 GEMM: bf16 MFMA, fused att logits ----------------
// one wave = 16 nodes x 128 ch; A = h1o (bf16, K-contig), B = w2p (N-major K-contig)
__global__ __launch_bounds__(256) void k_gemm2(const unsigned short* __restrict__ h1o,
                                               const unsigned short* __restrict__ w2p,
                                               const float* __restrict__ atts,
                                               const float* __restrict__ attd,
                                               unsigned short* __restrict__ h2bf,
                                               float* __restrict__ a_s,
                                               float* __restrict__ a_d) {
    int t = threadIdx.x;
    int wave = t >> 6, lane = t & 63;
    int m0 = (blockIdx.x * 4 + wave) * 16;
    if (m0 >= N_NODES) return;
    int l15 = lane & 15, quad = lane >> 4;
    f32x4 acc[8];
#pragma unroll
    for (int j = 0; j < 8; ++j) acc[j] = (f32x4){0.f, 0.f, 0.f, 0.f};
    const unsigned short* arow = h1o + (m0 + l15) * C1 + quad * 8;
#pragma unroll
    for (int k0 = 0; k0 < C1; k0 += 32) {
        short8 av = *(const short8*)(arow + k0);
#pragma unroll
        for (int j = 0; j < 8; ++j) {
            short8 bv = *(const short8*)(w2p + (j * 16 + l15) * C1 + k0 + quad * 8);
            acc[j] = __builtin_amdgcn_mfma_f32_16x16x32_bf16(av, bv, acc[j], 0, 0, 0);
        }
    }
    // D layout: row = quad*4 + r, col = j*16 + l15
    float ps[4] = {0.f, 0.f, 0.f, 0.f}, pd[4] = {0.f, 0.f, 0.f, 0.f};
#pragma unroll
    for (int j = 0; j < 8; ++j) {
        float as_ = atts[j * 16 + l15], ad_ = attd[j * 16 + l15];
#pragma unroll
        for (int r = 0; r < 4; ++r) {
            float v = acc[j][r];
            h2bf[(m0 + quad * 4 + r) * C2 + j * 16 + l15] = f2bfu(v);
            ps[r] += v * as_;
            pd[r] += v * ad_;
        }
    }
#pragma unroll
    for (int r = 0; r < 4; ++r) {
#pragma unroll
        for (int o = 8; o > 0; o >>= 1) {
            ps[r] += __shfl_down(ps[r], o, 16);
            pd[r] += __shfl_down(pd[r], o, 16);
        }
        if (l15 == 0) {
            int n = m0 + quad * 4 + r;
            a_s[n] = ps[r];
            a_d[n] = pd[r];
        }
    }
}

// ---------------- layer 2 aggregate + pool: fused softmax (no max) ----------------
__global__ __launch_bounds__(256) void k_l2_aggpool(const int* __restrict__ row_ptr,
                                                    const int* __restrict__ csrc,
                                                    const float* __restrict__ a_s,
                                                    const float* __restrict__ a_d,
                                                    const unsigned short* __restrict__ h2bf,
                                                    const float* __restrict__ b2,
                                                    const int* __restrict__ batch,
                                                    float* __restrict__ pooled) {
    int t = threadIdx.x;
    int d = blockIdx.x * 4 + (t >> 6);
    if (d >= N_NODES) return;
    int lane = t & 63;
    int beg = row_ptr[d], deg = row_ptr[d + 1] - beg;
    float ad = a_d[d];
    const unsigned* rows = (const unsigned*)h2bf;
    float a0 = 0.f, a1 = 0.f, z = 0.f;
    int i = 0;
    for (; i + 8 <= deg; i += 8) {
        int e0 = beg + i;
        int s[8]; unsigned u[8]; float ex[8];
#pragma unroll
        for (int k = 0; k < 8; ++k) s[k] = csrc[e0 + k];
#pragma unroll
        for (int k = 0; k < 8; ++k) u[k] = rows[s[k] * 64 + lane];
#pragma unroll
        for (int k = 0; k < 8; ++k) ex[k] = __expf(leaky(a_s[s[k]] + ad));
#pragma unroll
        for (int k = 0; k < 8; ++k) {
            z  += ex[k];
            a0 += ex[k] * lo16(u[k]);
            a1 += ex[k] * hi16(u[k]);
        }
    }
    for (; i < deg; ++i) {
        int s = csrc[beg + i];
        unsigned u = rows[s * 64 + lane];
        float ex = __expf(leaky(a_s[s] + ad));
        z  += ex;
        a0 += ex * lo16(u);
        a1 += ex * hi16(u);
    }
    float inv = 1.f / z;
    int c = lane * 2;
    float v0 = fmaxf(a0 * inv + b2[c], 0.f);
    float v1 = fmaxf(a1 * inv + b2[c + 1], 0.f);
    int g = batch[d];
    atomicAdd(&pooled[g * C2 + c], v0);
    atomicAdd(&pooled[g * C2 + c + 1], v1);
}

// ---------------- BN ----------------

__global__ __launch_bounds__(512) void k_bn(const float* __restrict__ pooled,
                                            const float* __restrict__ cnt,
                                            const float* __restrict__ gamma,
                                            const float* __restrict__ beta,
                                            float* __restrict__ out) {
    int c = blockIdx.x;
    int g = threadIdx.x;
    __shared__ float red[512];
    __shared__ float s_mu, s_var;
    float v = pooled[g * C2 + c] / fmaxf(cnt[g], 1.0f);
    red[g] = v;
    __syncthreads();
    for (int s = 256; s > 0; s >>= 1) {
        if (g < s) red[g] += red[g + s];
        __syncthreads();
    }
    if (g == 0) s_mu = red[0] * (1.0f / N_GRAPHS);
    __syncthreads();
    float dv = v - s_mu;
    red[g] = dv * dv;
    __syncthreads();
    for (int s = 256; s > 0; s >>= 1) {
        if (g < s) red[g] += red[g + s];
        __syncthreads();
    }
    if (g == 0) s_var = red[0] * (1.0f / N_GRAPHS);
    __syncthreads();
    out[g * C2 + c] = dv * rsqrtf(s_var + 1e-5f) * gamma[c] + beta[c];
}

extern "C" void kernel_launch(void* const* d_in, const int* in_sizes, int n_in,
                              void* d_out, int out_size, void* d_ws, size_t ws_size,
                              hipStream_t stream) {
    const float* x     = (const float*)d_in[0];
    const int*   eidx  = (const int*)d_in[1];
    const int*   batch = (const int*)d_in[2];
    const float* W1    = (const float*)d_in[3];
    const float* atts1 = (const float*)d_in[4];
    const float* attd1 = (const float*)d_in[5];
    const float* b1    = (const float*)d_in[6];
    const float* W2    = (const float*)d_in[7];
    const float* atts2 = (const float*)d_in[8];
    const float* attd2 = (const float*)d_in[9];
    const float* b2    = (const float*)d_in[10];
    const float* gamma = (const float*)d_in[11];
    const float* beta  = (const float*)d_in[12];
    float* out = (float*)d_out;
    float* ws  = (float*)d_ws;

    const int* src = eidx;
    const int* dst = eidx + N_EDGES;

    // workspace layout, float-element offsets
    const size_t o_h1bf   = 0;           // 12.8M bf16 = 6,400,000 floats
    const size_t o_h1o    = 6400000;     // 12.8M bf16 = 6,400,000 floats
    const size_t o_h2bf   = 12800000;    // 6.4M bf16 = 3,200,000 floats
    const size_t o_w2p    = 16000000;    // 32,768 bf16 = 16,384 floats
    const size_t o_as1    = 16016384;    // 200,000
    const size_t o_ad1    = 16216384;    // 200,000
    const size_t o_as2    = 16416384;    // 50,000
    const size_t o_ad2    = 16466384;    // 50,000
    const size_t o_incl   = 16516384;    // 50,176
    const size_t o_bsum   = 16566560;    // 256
    const size_t o_boff   = 16566816;    // 256
    const size_t o_rowptr = 16567072;    // 50,004
    const size_t o_csrc   = 16617076;    // 850,000
    // ---- contiguous zero block from here ----
    const size_t o_deg    = 17467076;    // 50,176
    const size_t o_cursor = 17517252;    // 50,000
    const size_t o_pool   = 17567252;    // 65,536
    const size_t o_cnt    = 17632788;    // 512
    const size_t total    = 17633300;    // ~70.5 MB

    int* p_incl   = (int*)(ws + o_incl);
    int* p_bsum   = (int*)(ws + o_bsum);
    int* p_boff   = (int*)(ws + o_boff);
    int* p_rowptr = (int*)(ws + o_rowptr);
    int* p_csrc   = (int*)(ws + o_csrc);
    int* p_deg    = (int*)(ws + o_deg);
    int* p_cursor = (int*)(ws + o_cursor);
    __hip_bfloat16* p_h1bf = (__hip_bfloat16*)(ws + o_h1bf);
    unsigned short* p_h1o  = (unsigned short*)(ws + o_h1o);
    unsigned short* p_h2bf = (unsigned short*)(ws + o_h2bf);
    __hip_bfloat16* p_w2p  = (__hip_bfloat16*)(ws + o_w2p);

    hipMemsetAsync(ws + o_deg, 0, (total - o_deg) * sizeof(float), stream);

    // ---- CSR build ----
    k_hist<<<(E_TOT + 255) / 256, 256, 0, stream>>>(src, dst, p_deg);
    k_scan1<<<NBLK, 256, 0, stream>>>(p_deg, p_incl, p_bsum);
    k_scan2<<<1, 256, 0, stream>>>(p_bsum, p_boff);
    k_scan3<<<NBLK, 256, 0, stream>>>(p_incl, p_boff, batch, p_rowptr, ws + o_cnt);
    k_scatter<<<(E_TOT + 255) / 256, 256, 0, stream>>>(src, dst, p_rowptr, p_cursor, p_csrc);
    k_prepw<<<C2, 256, 0, stream>>>(W2, p_w2p);

    const int nwb = (N_NODES + 3) / 4;

    // ---- layer 1 ----
    k_gemm1<<<(N_NODES + 63) / 64, 256, 0, stream>>>(x, W1, atts1, attd1,
                                                     p_h1bf, ws + o_as1, ws + o_ad1);
    k_l1_agg<<<nwb, 256, 0, stream>>>(p_rowptr, p_csrc, ws + o_as1, ws + o_ad1,
                                      p_h1bf, b1, p_h1o);

    // ---- layer 2 ----
    const int nmfma = (N_NODES / 16 + 3) / 4;   // 3125 waves, 4 per block
    k_gemm2<<<nmfma, 256, 0, stream>>>(p_h1o, (const unsigned short*)p_w2p, atts2, attd2,
                                       p_h2bf, ws + o_as2, ws + o_ad2);
    k_l2_aggpool<<<nwb, 256, 0, stream>>>(p_rowptr, p_csrc, ws + o_as2, ws + o_ad2,
                                          p_h2bf, b2, batch, ws + o_pool);

    // ---- BN ----
    k_bn<<<C2, 512, 0, stream>>>(ws + o_pool, ws + o_cnt, gamma, beta, out);
}